// Round 1
// baseline (401.633 us; speedup 1.0000x reference)
//
#include <hip/hip_runtime.h>
#include <hip/hip_bf16.h>
#include <math.h>

using bf16 = __hip_bfloat16;
typedef short s16x8 __attribute__((ext_vector_type(8)));
typedef float f32x4 __attribute__((ext_vector_type(4)));

__device__ inline unsigned short f2bf(float f) {
    bf16 h = __float2bfloat16(f);
    return __builtin_bit_cast(unsigned short, h);
}

// ---------------------------------------------------------------------------
// Weight prep: in [K][N] fp32 row-major  ->  out [N][K] bf16 row-major (W^T)
// ---------------------------------------------------------------------------
__global__ __launch_bounds__(256) void transpose_bf16(
    const float* __restrict__ in, bf16* __restrict__ out, int K, int N)
{
    __shared__ float tile[32][33];
    const int bx = blockIdx.x * 32;  // n
    const int by = blockIdx.y * 32;  // k
    const int tx = threadIdx.x, ty = threadIdx.y;  // 32 x 8
    #pragma unroll
    for (int i = 0; i < 32; i += 8)
        tile[ty + i][tx] = in[(size_t)(by + ty + i) * N + bx + tx];
    __syncthreads();
    #pragma unroll
    for (int i = 0; i < 32; i += 8)
        out[(size_t)(bx + ty + i) * K + by + tx] = __float2bfloat16(tile[tx][ty + i]);
}

// ---------------------------------------------------------------------------
// LayerNorm over C=768, fp32 in -> bf16 out. One 256-thread block per row.
// ---------------------------------------------------------------------------
__global__ __launch_bounds__(256) void ln_kernel(
    const float* __restrict__ x, const float* __restrict__ g,
    const float* __restrict__ bb, bf16* __restrict__ out)
{
    const int row = blockIdx.x;
    const float* xr = x + (size_t)row * 768;
    float v[3];
    float s = 0.f, s2 = 0.f;
    #pragma unroll
    for (int i = 0; i < 3; ++i) {
        v[i] = xr[threadIdx.x + i * 256];
        s += v[i];
        s2 += v[i] * v[i];
    }
    #pragma unroll
    for (int off = 1; off < 64; off <<= 1) {
        s += __shfl_xor(s, off);
        s2 += __shfl_xor(s2, off);
    }
    __shared__ float rs[4], rs2[4];
    const int wave = threadIdx.x >> 6;
    if ((threadIdx.x & 63) == 0) { rs[wave] = s; rs2[wave] = s2; }
    __syncthreads();
    s = rs[0] + rs[1] + rs[2] + rs[3];
    s2 = rs2[0] + rs2[1] + rs2[2] + rs2[3];
    const float mu = s * (1.f / 768.f);
    const float var = s2 * (1.f / 768.f) - mu * mu;
    const float r = rsqrtf(var + 1e-6f);
    bf16* orow = out + (size_t)row * 768;
    #pragma unroll
    for (int i = 0; i < 3; ++i) {
        const int col = threadIdx.x + i * 256;
        orow[col] = __float2bfloat16((v[i] - mu) * r * g[col] + bb[col]);
    }
}

// ---------------------------------------------------------------------------
// GEMM: out[M][N] = A[M][K] @ Bt[N][K]^T + bias (+ residual / gelu)
// A, Bt bf16; bias fp32; 128x128 tile, BK=64, 4 waves, 16x16x32 MFMA.
// EPI: 0 = bias -> bf16 out ; 1 = bias+resid -> fp32 out ; 2 = bias+gelu -> bf16
// ---------------------------------------------------------------------------
#define BM 128
#define BN 128
#define BK 64

template <int EPI>
__global__ __launch_bounds__(256) void gemm_bt(
    const bf16* __restrict__ A, const bf16* __restrict__ Bt,
    const float* __restrict__ bias, const float* __restrict__ resid,
    void* __restrict__ outp, int M, int N, int K)
{
    __shared__ alignas(16) char As[BM * BK * 2];
    __shared__ alignas(16) char Bs[BN * BK * 2];
    const int tid = threadIdx.x;
    const int lane = tid & 63;
    const int wave = tid >> 6;
    const int wm = wave >> 1, wn = wave & 1;
    const int lr = lane & 15, lg = lane >> 4;
    const int bm = blockIdx.x, bn = blockIdx.y;

    f32x4 acc[4][4] = {};

    const size_t a_row0 = (size_t)bm * BM;
    const size_t b_row0 = (size_t)bn * BN;

    for (int kt = 0; kt < K; kt += BK) {
        // stage A and B tiles (reg-staged, XOR-swizzled 16B chunks)
        #pragma unroll
        for (int i = 0; i < 4; ++i) {
            const int id = tid + i * 256;
            const int row = id >> 3, c = id & 7;
            const int4 va = *reinterpret_cast<const int4*>(A + (a_row0 + row) * K + kt + c * 8);
            *reinterpret_cast<int4*>(As + row * 128 + ((c ^ (row & 7)) * 16)) = va;
            const int4 vb = *reinterpret_cast<const int4*>(Bt + (b_row0 + row) * K + kt + c * 8);
            *reinterpret_cast<int4*>(Bs + row * 128 + ((c ^ (row & 7)) * 16)) = vb;
        }
        __syncthreads();
        #pragma unroll
        for (int ks = 0; ks < 2; ++ks) {
            s16x8 af[4], bfr[4];
            #pragma unroll
            for (int mf = 0; mf < 4; ++mf) {
                const int row = wm * 64 + mf * 16 + lr;
                const int c = ks * 4 + lg;
                af[mf] = *reinterpret_cast<const s16x8*>(As + row * 128 + ((c ^ (row & 7)) * 16));
            }
            #pragma unroll
            for (int nf = 0; nf < 4; ++nf) {
                const int row = wn * 64 + nf * 16 + lr;
                const int c = ks * 4 + lg;
                bfr[nf] = *reinterpret_cast<const s16x8*>(Bs + row * 128 + ((c ^ (row & 7)) * 16));
            }
            #pragma unroll
            for (int mf = 0; mf < 4; ++mf)
                #pragma unroll
                for (int nf = 0; nf < 4; ++nf)
                    acc[mf][nf] = __builtin_amdgcn_mfma_f32_16x16x32_bf16(
                        af[mf], bfr[nf], acc[mf][nf], 0, 0, 0);
        }
        __syncthreads();
    }

    // epilogue: D layout col = lane&15, row = 4*(lane>>4)+i
    #pragma unroll
    for (int mf = 0; mf < 4; ++mf) {
        #pragma unroll
        for (int i = 0; i < 4; ++i) {
            const int gm = bm * BM + wm * 64 + mf * 16 + 4 * lg + i;
            #pragma unroll
            for (int nf = 0; nf < 4; ++nf) {
                const int gn = bn * BN + wn * 64 + nf * 16 + lr;
                float v = acc[mf][nf][i] + bias[gn];
                if (EPI == 1) v += resid[(size_t)gm * N + gn];
                if (EPI == 2) v = 0.5f * v * (1.0f + erff(v * 0.70710678118654752f));
                if (EPI == 1)
                    reinterpret_cast<float*>(outp)[(size_t)gm * N + gn] = v;
                else
                    reinterpret_cast<bf16*>(outp)[(size_t)gm * N + gn] = __float2bfloat16(v);
            }
        }
    }
}

// ---------------------------------------------------------------------------
// Flash attention. qkv [B*N][2304] bf16 (q|k|v each [H=12][D=64]).
// Grid (32 qblocks, 12 heads, 4 batch), 256 threads = 4 waves.
// Each wave owns 16 q-rows; KV tiles of 64; online softmax.
// Mask semantics: mask[b, q]==0 -> whole score row = -inf -> uniform softmax.
// Output: [B*N][768] bf16, token-major (ready for proj GEMM).
// ---------------------------------------------------------------------------
__global__ __launch_bounds__(256) void attn_kernel(
    const bf16* __restrict__ qkv, const int* __restrict__ mask,
    bf16* __restrict__ out)
{
    __shared__ alignas(16) char Ks[64 * 128];        // 64 keys x 64 d, swizzled
    __shared__ alignas(16) char Vt[64 * 128];        // 64 d x 64 keys, swizzled
    __shared__ alignas(16) char Ps[4 * 16 * 128];    // per-wave P: 16 q x 64 keys

    const int qb = blockIdx.x, h = blockIdx.y, b = blockIdx.z;
    const int tid = threadIdx.x, lane = tid & 63, wave = tid >> 6;
    const int lr = lane & 15, lg = lane >> 4;
    const bf16* qkvb = qkv + (size_t)b * 2048 * 2304;
    const int q0 = qb * 64 + wave * 16;

    // Q fragments (held in registers for the whole kernel)
    s16x8 qf[2];
    {
        const bf16* qp = qkvb + (size_t)(q0 + lr) * 2304 + h * 64 + 8 * lg;
        qf[0] = *reinterpret_cast<const s16x8*>(qp);
        qf[1] = *reinterpret_cast<const s16x8*>(qp + 32);
    }
    int mrow[4];
    #pragma unroll
    for (int i = 0; i < 4; ++i) mrow[i] = mask[b * 2048 + q0 + 4 * lg + i];

    float m_r[4] = {-1e30f, -1e30f, -1e30f, -1e30f};
    float l_r[4] = {0.f, 0.f, 0.f, 0.f};
    f32x4 o[4] = {};

    char* Pw = Ps + wave * (16 * 128);

    for (int kb = 0; kb < 32; ++kb) {
        // ---- stage K tile (natural [key][d], swizzled 16B chunks) ----
        #pragma unroll
        for (int i = 0; i < 2; ++i) {
            const int id = tid + i * 256;
            const int row = id >> 3, c = id & 7;
            const int4 vk = *reinterpret_cast<const int4*>(
                qkvb + (size_t)(kb * 64 + row) * 2304 + 768 + h * 64 + c * 8);
            *reinterpret_cast<int4*>(Ks + row * 128 + ((c ^ (row & 7)) * 16)) = vk;
        }
        // ---- stage V transposed: Vt[d][key] ----
        #pragma unroll
        for (int i = 0; i < 2; ++i) {
            const int id = tid + i * 256;
            const int d = id & 63, kc = id >> 6;
            unsigned short tmp[8];
            #pragma unroll
            for (int j = 0; j < 8; ++j) {
                bf16 vv = qkvb[(size_t)(kb * 64 + kc * 8 + j) * 2304 + 1536 + h * 64 + d];
                tmp[j] = __builtin_bit_cast(unsigned short, vv);
            }
            *reinterpret_cast<int4*>(Vt + d * 128 + ((kc ^ (d & 7)) * 16)) =
                *reinterpret_cast<const int4*>(tmp);
        }
        __syncthreads();

        // ---- S = Q K^T  (per wave: 16 q x 64 keys) ----
        f32x4 s[4];
        #pragma unroll
        for (int nf = 0; nf < 4; ++nf) {
            const int row = nf * 16 + lr;
            const s16x8 kf0 = *reinterpret_cast<const s16x8*>(
                Ks + row * 128 + ((lg ^ (row & 7)) * 16));
            const s16x8 kf1 = *reinterpret_cast<const s16x8*>(
                Ks + row * 128 + (((4 + lg) ^ (row & 7)) * 16));
            f32x4 z = {};
            z = __builtin_amdgcn_mfma_f32_16x16x32_bf16(qf[0], kf0, z, 0, 0, 0);
            z = __builtin_amdgcn_mfma_f32_16x16x32_bf16(qf[1], kf1, z, 0, 0, 0);
            s[nf] = z;
        }

        // ---- online softmax ----
        float pv[4][4];  // [key-frag][row-reg]
        #pragma unroll
        for (int nf = 0; nf < 4; ++nf)
            #pragma unroll
            for (int i = 0; i < 4; ++i) {
                const float sv = s[nf][i] * 0.125f;  // D^-0.5
                pv[nf][i] = (mrow[i] == 0) ? -1e30f : sv;
            }
        #pragma unroll
        for (int i = 0; i < 4; ++i) {
            float tm = fmaxf(fmaxf(pv[0][i], pv[1][i]), fmaxf(pv[2][i], pv[3][i]));
            tm = fmaxf(tm, __shfl_xor(tm, 1));
            tm = fmaxf(tm, __shfl_xor(tm, 2));
            tm = fmaxf(tm, __shfl_xor(tm, 4));
            tm = fmaxf(tm, __shfl_xor(tm, 8));
            const float mnew = fmaxf(m_r[i], tm);
            const float alpha = __expf(m_r[i] - mnew);
            m_r[i] = mnew;
            float rs = 0.f;
            #pragma unroll
            for (int nf = 0; nf < 4; ++nf) {
                const float p = __expf(pv[nf][i] - mnew);
                pv[nf][i] = p;
                rs += p;
            }
            rs += __shfl_xor(rs, 1);
            rs += __shfl_xor(rs, 2);
            rs += __shfl_xor(rs, 4);
            rs += __shfl_xor(rs, 8);
            l_r[i] = l_r[i] * alpha + rs;
            #pragma unroll
            for (int nf = 0; nf < 4; ++nf) o[nf][i] *= alpha;
        }

        // ---- write P (bf16) to per-wave LDS, swizzled ----
        #pragma unroll
        for (int nf = 0; nf < 4; ++nf) {
            const int col = nf * 16 + lr;
            const int c8 = col >> 3, ci = col & 7;
            #pragma unroll
            for (int i = 0; i < 4; ++i) {
                const int row = 4 * lg + i;
                *reinterpret_cast<unsigned short*>(
                    Pw + row * 128 + ((c8 ^ (row & 7)) * 16) + ci * 2) = f2bf(pv[nf][i]);
            }
        }
        // per-wave buffer: no cross-wave hazard, compiler handles lgkmcnt

        // ---- O += P V ----
        #pragma unroll
        for (int ks = 0; ks < 2; ++ks) {
            const int c = ks * 4 + lg;
            const s16x8 pa = *reinterpret_cast<const s16x8*>(
                Pw + lr * 128 + ((c ^ (lr & 7)) * 16));
            #pragma unroll
            for (int nf = 0; nf < 4; ++nf) {
                const int d = nf * 16 + lr;
                const s16x8 vf = *reinterpret_cast<const s16x8*>(
                    Vt + d * 128 + ((c ^ (d & 7)) * 16));
                o[nf] = __builtin_amdgcn_mfma_f32_16x16x32_bf16(pa, vf, o[nf], 0, 0, 0);
            }
        }
        __syncthreads();
    }

    // ---- write normalized output ----
    #pragma unroll
    for (int nf = 0; nf < 4; ++nf) {
        #pragma unroll
        for (int i = 0; i < 4; ++i) {
            const int q = q0 + 4 * lg + i;
            const int d = nf * 16 + lr;
            const float val = o[nf][i] / l_r[i];
            out[(size_t)(b * 2048 + q) * 768 + h * 64 + d] = __float2bfloat16(val);
        }
    }
}

// ---------------------------------------------------------------------------
// Launch
// ---------------------------------------------------------------------------
extern "C" void kernel_launch(void* const* d_in, const int* in_sizes, int n_in,
                              void* d_out, int out_size, void* d_ws, size_t ws_size,
                              hipStream_t stream)
{
    (void)in_sizes; (void)n_in; (void)out_size; (void)ws_size;
    const float* x      = (const float*)d_in[0];
    const int*   mask   = (const int*)d_in[1];
    const float* ln1_g  = (const float*)d_in[2];
    const float* ln1_b  = (const float*)d_in[3];
    const float* qkv_w  = (const float*)d_in[4];
    const float* qkv_b  = (const float*)d_in[5];
    const float* proj_w = (const float*)d_in[6];
    const float* proj_b = (const float*)d_in[7];
    const float* ln2_g  = (const float*)d_in[8];
    const float* ln2_b  = (const float*)d_in[9];
    const float* fc1_w  = (const float*)d_in[10];
    const float* fc1_b  = (const float*)d_in[11];
    const float* fc2_w  = (const float*)d_in[12];
    const float* fc2_b  = (const float*)d_in[13];
    float* out = (float*)d_out;
    char* ws = (char*)d_ws;

    bf16*  Wt_qkv  = (bf16*)(ws + 0);          // [2304][768]
    bf16*  Wt_proj = (bf16*)(ws + 3538944);    // [768][768]
    bf16*  Wt_fc1  = (bf16*)(ws + 4718592);    // [3072][768]
    bf16*  Wt_fc2  = (bf16*)(ws + 9437184);    // [768][3072]
    bf16*  hbuf    = (bf16*)(ws + 14155776);   // [8192][768]
    bf16*  qkvbuf  = (bf16*)(ws + 26738688);   // [8192][2304]
    bf16*  attnout = (bf16*)(ws + 64487424);   // [8192][768]
    float* x1      = (float*)(ws + 77070336);  // [8192][768]
    bf16*  h2      = (bf16*)(ws + 102236160);  // [8192][768]
    bf16*  a1      = (bf16*)(ws + 114819072);  // [8192][3072]

    const dim3 tb(32, 8);
    transpose_bf16<<<dim3(2304 / 32, 768 / 32), tb, 0, stream>>>(qkv_w, Wt_qkv, 768, 2304);
    transpose_bf16<<<dim3(768 / 32, 768 / 32), tb, 0, stream>>>(proj_w, Wt_proj, 768, 768);
    transpose_bf16<<<dim3(3072 / 32, 768 / 32), tb, 0, stream>>>(fc1_w, Wt_fc1, 768, 3072);
    transpose_bf16<<<dim3(768 / 32, 3072 / 32), tb, 0, stream>>>(fc2_w, Wt_fc2, 3072, 768);

    ln_kernel<<<8192, 256, 0, stream>>>(x, ln1_g, ln1_b, hbuf);
    gemm_bt<0><<<dim3(64, 18), 256, 0, stream>>>(hbuf, Wt_qkv, qkv_b, nullptr, qkvbuf, 8192, 2304, 768);
    attn_kernel<<<dim3(32, 12, 4), 256, 0, stream>>>(qkvbuf, mask, attnout);
    gemm_bt<1><<<dim3(64, 6), 256, 0, stream>>>(attnout, Wt_proj, proj_b, x, x1, 8192, 768, 768);
    ln_kernel<<<8192, 256, 0, stream>>>(x1, ln2_g, ln2_b, h2);
    gemm_bt<2><<<dim3(64, 24), 256, 0, stream>>>(h2, Wt_fc1, fc1_b, nullptr, a1, 8192, 3072, 768);
    gemm_bt<1><<<dim3(64, 6), 256, 0, stream>>>(a1, Wt_fc2, fc2_b, x1, out, 8192, 768, 3072);
}

// Round 2
// 384.298 us; speedup vs baseline: 1.0451x; 1.0451x over previous
//
#include <hip/hip_runtime.h>
#include <hip/hip_bf16.h>
#include <math.h>

using bf16 = __hip_bfloat16;
typedef short s16x8 __attribute__((ext_vector_type(8)));
typedef float f32x4 __attribute__((ext_vector_type(4)));

__device__ inline unsigned short f2bf(float f) {
    bf16 h = __float2bfloat16(f);
    return __builtin_bit_cast(unsigned short, h);
}

// async global->LDS, 16B per lane. Dest must be wave-linear (base + lane*16).
__device__ inline void gload_lds16(const void* g, void* l) {
    __builtin_amdgcn_global_load_lds(
        (const __attribute__((address_space(1))) void*)g,
        (__attribute__((address_space(3))) void*)l, 16, 0, 0);
}

// ---------------------------------------------------------------------------
// Weight prep: in [K][N] fp32 row-major  ->  out [N][K] bf16 row-major (W^T)
// ---------------------------------------------------------------------------
__global__ __launch_bounds__(256) void transpose_bf16(
    const float* __restrict__ in, bf16* __restrict__ out, int K, int N)
{
    __shared__ float tile[32][33];
    const int bx = blockIdx.x * 32;  // n
    const int by = blockIdx.y * 32;  // k
    const int tx = threadIdx.x, ty = threadIdx.y;  // 32 x 8
    #pragma unroll
    for (int i = 0; i < 32; i += 8)
        tile[ty + i][tx] = in[(size_t)(by + ty + i) * N + bx + tx];
    __syncthreads();
    #pragma unroll
    for (int i = 0; i < 32; i += 8)
        out[(size_t)(bx + ty + i) * K + by + tx] = __float2bfloat16(tile[tx][ty + i]);
}

// ---------------------------------------------------------------------------
// LayerNorm over C=768, fp32 in -> bf16 out. One 256-thread block per row.
// ---------------------------------------------------------------------------
__global__ __launch_bounds__(256) void ln_kernel(
    const float* __restrict__ x, const float* __restrict__ g,
    const float* __restrict__ bb, bf16* __restrict__ out)
{
    const int row = blockIdx.x;
    const float* xr = x + (size_t)row * 768;
    float v[3];
    float s = 0.f, s2 = 0.f;
    #pragma unroll
    for (int i = 0; i < 3; ++i) {
        v[i] = xr[threadIdx.x + i * 256];
        s += v[i];
        s2 += v[i] * v[i];
    }
    #pragma unroll
    for (int off = 1; off < 64; off <<= 1) {
        s += __shfl_xor(s, off);
        s2 += __shfl_xor(s2, off);
    }
    __shared__ float rs[4], rs2[4];
    const int wave = threadIdx.x >> 6;
    if ((threadIdx.x & 63) == 0) { rs[wave] = s; rs2[wave] = s2; }
    __syncthreads();
    s = rs[0] + rs[1] + rs[2] + rs[3];
    s2 = rs2[0] + rs2[1] + rs2[2] + rs2[3];
    const float mu = s * (1.f / 768.f);
    const float var = s2 * (1.f / 768.f) - mu * mu;
    const float r = rsqrtf(var + 1e-6f);
    bf16* orow = out + (size_t)row * 768;
    #pragma unroll
    for (int i = 0; i < 3; ++i) {
        const int col = threadIdx.x + i * 256;
        orow[col] = __float2bfloat16((v[i] - mu) * r * g[col] + bb[col]);
    }
}

// ---------------------------------------------------------------------------
// QKV rearrange: qkv [B*N][2304] -> Qb [B][H][N][D] (pre-scaled by D^-0.5),
// Kb [B][H][N][D], Vt [B][H][D][N]. All coalesced; V transposed via LDS.
// ---------------------------------------------------------------------------
__global__ __launch_bounds__(256) void qkv_rearrange(
    const bf16* __restrict__ qkv, bf16* __restrict__ Qb,
    bf16* __restrict__ Kb, bf16* __restrict__ Vt)
{
    const int nt = blockIdx.x, h = blockIdx.y, b = blockIdx.z;
    const int tid = threadIdx.x;
    const size_t bh = (size_t)(b * 12 + h);
    const int n0 = nt * 64;

    __shared__ unsigned short vtile[64][65];

    #pragma unroll
    for (int i = 0; i < 2; ++i) {
        const int id = tid + i * 256;
        const int row = id >> 3, c = id & 7;
        const size_t src = (size_t)(b * 2048 + n0 + row) * 2304 + h * 64 + c * 8;
        // Q, scaled by 0.125 (exact exponent shift in bf16)
        unsigned short tq[8];
        *reinterpret_cast<int4*>(tq) = *reinterpret_cast<const int4*>(qkv + src);
        #pragma unroll
        for (int j = 0; j < 8; ++j)
            tq[j] = f2bf(__bfloat162float(__builtin_bit_cast(bf16, tq[j])) * 0.125f);
        *reinterpret_cast<int4*>(Qb + (bh * 2048 + n0 + row) * 64 + c * 8) =
            *reinterpret_cast<const int4*>(tq);
        // K straight copy
        *reinterpret_cast<int4*>(Kb + (bh * 2048 + n0 + row) * 64 + c * 8) =
            *reinterpret_cast<const int4*>(qkv + src + 768);
        // V into LDS tile
        unsigned short tv[8];
        *reinterpret_cast<int4*>(tv) = *reinterpret_cast<const int4*>(qkv + src + 1536);
        #pragma unroll
        for (int j = 0; j < 8; ++j) vtile[row][c * 8 + j] = tv[j];
    }
    __syncthreads();
    #pragma unroll
    for (int i = 0; i < 2; ++i) {
        const int id = tid + i * 256;
        const int d = id >> 3, c = id & 7;
        unsigned short tmp[8];
        #pragma unroll
        for (int j = 0; j < 8; ++j) tmp[j] = vtile[c * 8 + j][d];
        *reinterpret_cast<int4*>(Vt + (bh * 64 + d) * 2048 + n0 + c * 8) =
            *reinterpret_cast<const int4*>(tmp);
    }
}

// ---------------------------------------------------------------------------
// GEMM: out[M][N] = A[M][K] @ Bt[N][K]^T + bias (+ residual / gelu)
// A, Bt bf16; 128x128 tile, BK=64, 4 waves, 16x16x32 MFMA.
// Staging via global_load_lds (linear dest, inverse-swizzled source).
// EPI: 0 = bias -> bf16 ; 1 = bias+resid -> fp32 ; 2 = bias+gelu -> bf16
// ---------------------------------------------------------------------------
#define BM 128
#define BN 128
#define BK 64

template <int EPI>
__global__ __launch_bounds__(256) void gemm_bt(
    const bf16* __restrict__ A, const bf16* __restrict__ Bt,
    const float* __restrict__ bias, const float* __restrict__ resid,
    void* __restrict__ outp, int M, int N, int K)
{
    __shared__ alignas(16) char As[BM * BK * 2];
    __shared__ alignas(16) char Bs[BN * BK * 2];
    const int tid = threadIdx.x;
    const int lane = tid & 63;
    const int wave = tid >> 6;
    const int wm = wave >> 1, wn = wave & 1;
    const int lr = lane & 15, lg = lane >> 4;
    const int bm = blockIdx.x, bn = blockIdx.y;

    f32x4 acc[4][4] = {};

    const size_t a_row0 = (size_t)bm * BM;
    const size_t b_row0 = (size_t)bn * BN;

    for (int kt = 0; kt < K; kt += BK) {
        #pragma unroll
        for (int i = 0; i < 4; ++i) {
            const int id = tid + i * 256;
            const int row = id >> 3, c = id & 7;
            const int cs = (c ^ (row & 7)) * 8;  // inverse swizzle on source
            gload_lds16(A + (a_row0 + row) * K + kt + cs, As + id * 16);
            gload_lds16(Bt + (b_row0 + row) * K + kt + cs, Bs + id * 16);
        }
        __syncthreads();
        #pragma unroll
        for (int ks = 0; ks < 2; ++ks) {
            s16x8 af[4], bfr[4];
            #pragma unroll
            for (int mf = 0; mf < 4; ++mf) {
                const int row = wm * 64 + mf * 16 + lr;
                const int c = ks * 4 + lg;
                af[mf] = *reinterpret_cast<const s16x8*>(As + row * 128 + ((c ^ (row & 7)) * 16));
            }
            #pragma unroll
            for (int nf = 0; nf < 4; ++nf) {
                const int row = wn * 64 + nf * 16 + lr;
                const int c = ks * 4 + lg;
                bfr[nf] = *reinterpret_cast<const s16x8*>(Bs + row * 128 + ((c ^ (row & 7)) * 16));
            }
            #pragma unroll
            for (int mf = 0; mf < 4; ++mf)
                #pragma unroll
                for (int nf = 0; nf < 4; ++nf)
                    acc[mf][nf] = __builtin_amdgcn_mfma_f32_16x16x32_bf16(
                        af[mf], bfr[nf], acc[mf][nf], 0, 0, 0);
        }
        __syncthreads();
    }

    #pragma unroll
    for (int mf = 0; mf < 4; ++mf) {
        #pragma unroll
        for (int i = 0; i < 4; ++i) {
            const int gm = bm * BM + wm * 64 + mf * 16 + 4 * lg + i;
            #pragma unroll
            for (int nf = 0; nf < 4; ++nf) {
                const int gn = bn * BN + wn * 64 + nf * 16 + lr;
                float v = acc[mf][nf][i] + bias[gn];
                if (EPI == 1) v += resid[(size_t)gm * N + gn];
                if (EPI == 2) v = 0.5f * v * (1.0f + erff(v * 0.70710678118654752f));
                if (EPI == 1)
                    reinterpret_cast<float*>(outp)[(size_t)gm * N + gn] = v;
                else
                    reinterpret_cast<bf16*>(outp)[(size_t)gm * N + gn] = __float2bfloat16(v);
            }
        }
    }
}

// ---------------------------------------------------------------------------
// Flash attention. Qb/Kb [B][H][N][D] (Q pre-scaled), Vt [B][H][D][N], bf16.
// Grid (32 qblocks, 12 heads, 4 batch), 256 threads = 4 waves, 16 q-rows/wave.
// Output: [B*N][768] bf16 token-major.
// ---------------------------------------------------------------------------
__global__ __launch_bounds__(256) void attn_kernel(
    const bf16* __restrict__ Qb, const bf16* __restrict__ Kb,
    const bf16* __restrict__ Vt, const int* __restrict__ mask,
    bf16* __restrict__ out)
{
    __shared__ alignas(16) char Ks[64 * 128];      // [key][d] swizzled
    __shared__ alignas(16) char Vs[64 * 128];      // [d][key] swizzled
    __shared__ alignas(16) char Ps[4 * 16 * 128];  // per-wave P: 16 q x 64 keys

    const int qb = blockIdx.x, h = blockIdx.y, b = blockIdx.z;
    const int tid = threadIdx.x, lane = tid & 63, wave = tid >> 6;
    const int lr = lane & 15, lg = lane >> 4;
    const size_t bh = (size_t)(b * 12 + h);
    const bf16* Kh = Kb + bh * 2048 * 64;
    const bf16* Vh = Vt + bh * 64 * 2048;
    const int q0 = qb * 64 + wave * 16;

    s16x8 qf[2];
    {
        const bf16* qp = Qb + (bh * 2048 + q0 + lr) * 64 + 8 * lg;
        qf[0] = *reinterpret_cast<const s16x8*>(qp);
        qf[1] = *reinterpret_cast<const s16x8*>(qp + 32);
    }
    int mrow[4];
    #pragma unroll
    for (int i = 0; i < 4; ++i) mrow[i] = mask[b * 2048 + q0 + 4 * lg + i];

    float m_r[4] = {-1e30f, -1e30f, -1e30f, -1e30f};
    float l_r[4] = {0.f, 0.f, 0.f, 0.f};
    f32x4 o[4] = {};

    char* Pw = Ps + wave * (16 * 128);

    for (int kb = 0; kb < 32; ++kb) {
        // stage K and V^T tiles: coalesced async, inverse-swizzled source
        #pragma unroll
        for (int i = 0; i < 2; ++i) {
            const int id = tid + i * 256;
            const int row = id >> 3, c = id & 7;
            const int cs = (c ^ (row & 7)) * 8;
            gload_lds16(Kh + (size_t)(kb * 64 + row) * 64 + cs, Ks + id * 16);
            gload_lds16(Vh + (size_t)row * 2048 + kb * 64 + cs, Vs + id * 16);
        }
        __syncthreads();

        // S = Q K^T (per wave: 16 q x 64 keys)
        f32x4 s[4];
        #pragma unroll
        for (int nf = 0; nf < 4; ++nf) {
            const int row = nf * 16 + lr;
            const s16x8 kf0 = *reinterpret_cast<const s16x8*>(
                Ks + row * 128 + ((lg ^ (row & 7)) * 16));
            const s16x8 kf1 = *reinterpret_cast<const s16x8*>(
                Ks + row * 128 + (((4 + lg) ^ (row & 7)) * 16));
            f32x4 z = {};
            z = __builtin_amdgcn_mfma_f32_16x16x32_bf16(qf[0], kf0, z, 0, 0, 0);
            z = __builtin_amdgcn_mfma_f32_16x16x32_bf16(qf[1], kf1, z, 0, 0, 0);
            s[nf] = z;
        }

        // online softmax
        float pv[4][4];
        #pragma unroll
        for (int nf = 0; nf < 4; ++nf)
            #pragma unroll
            for (int i = 0; i < 4; ++i)
                pv[nf][i] = (mrow[i] == 0) ? -1e30f : s[nf][i];
        #pragma unroll
        for (int i = 0; i < 4; ++i) {
            float tm = fmaxf(fmaxf(pv[0][i], pv[1][i]), fmaxf(pv[2][i], pv[3][i]));
            tm = fmaxf(tm, __shfl_xor(tm, 1));
            tm = fmaxf(tm, __shfl_xor(tm, 2));
            tm = fmaxf(tm, __shfl_xor(tm, 4));
            tm = fmaxf(tm, __shfl_xor(tm, 8));
            const float mnew = fmaxf(m_r[i], tm);
            const float alpha = __expf(m_r[i] - mnew);
            m_r[i] = mnew;
            float rs = 0.f;
            #pragma unroll
            for (int nf = 0; nf < 4; ++nf) {
                const float p = __expf(pv[nf][i] - mnew);
                pv[nf][i] = p;
                rs += p;
            }
            rs += __shfl_xor(rs, 1);
            rs += __shfl_xor(rs, 2);
            rs += __shfl_xor(rs, 4);
            rs += __shfl_xor(rs, 8);
            l_r[i] = l_r[i] * alpha + rs;
            #pragma unroll
            for (int nf = 0; nf < 4; ++nf) o[nf][i] *= alpha;
        }

        // write P (bf16) to per-wave LDS, swizzled
        #pragma unroll
        for (int nf = 0; nf < 4; ++nf) {
            const int col = nf * 16 + lr;
            const int c8 = col >> 3, ci = col & 7;
            #pragma unroll
            for (int i = 0; i < 4; ++i) {
                const int row = 4 * lg + i;
                *reinterpret_cast<unsigned short*>(
                    Pw + row * 128 + ((c8 ^ (row & 7)) * 16) + ci * 2) = f2bf(pv[nf][i]);
            }
        }

        // O += P V
        #pragma unroll
        for (int ks = 0; ks < 2; ++ks) {
            const int c = ks * 4 + lg;
            const s16x8 pa = *reinterpret_cast<const s16x8*>(
                Pw + lr * 128 + ((c ^ (lr & 7)) * 16));
            #pragma unroll
            for (int nf = 0; nf < 4; ++nf) {
                const int d = nf * 16 + lr;
                const s16x8 vf = *reinterpret_cast<const s16x8*>(
                    Vs + d * 128 + ((c ^ (d & 7)) * 16));
                o[nf] = __builtin_amdgcn_mfma_f32_16x16x32_bf16(pa, vf, o[nf], 0, 0, 0);
            }
        }
        __syncthreads();
    }

    #pragma unroll
    for (int nf = 0; nf < 4; ++nf) {
        #pragma unroll
        for (int i = 0; i < 4; ++i) {
            const int q = q0 + 4 * lg + i;
            const int d = nf * 16 + lr;
            const float val = o[nf][i] / l_r[i];
            out[(size_t)(b * 2048 + q) * 768 + h * 64 + d] = __float2bfloat16(val);
        }
    }
}

// ---------------------------------------------------------------------------
// Launch
// ---------------------------------------------------------------------------
extern "C" void kernel_launch(void* const* d_in, const int* in_sizes, int n_in,
                              void* d_out, int out_size, void* d_ws, size_t ws_size,
                              hipStream_t stream)
{
    (void)in_sizes; (void)n_in; (void)out_size; (void)ws_size;
    const float* x      = (const float*)d_in[0];
    const int*   mask   = (const int*)d_in[1];
    const float* ln1_g  = (const float*)d_in[2];
    const float* ln1_b  = (const float*)d_in[3];
    const float* qkv_w  = (const float*)d_in[4];
    const float* qkv_b  = (const float*)d_in[5];
    const float* proj_w = (const float*)d_in[6];
    const float* proj_b = (const float*)d_in[7];
    const float* ln2_g  = (const float*)d_in[8];
    const float* ln2_b  = (const float*)d_in[9];
    const float* fc1_w  = (const float*)d_in[10];
    const float* fc1_b  = (const float*)d_in[11];
    const float* fc2_w  = (const float*)d_in[12];
    const float* fc2_b  = (const float*)d_in[13];
    float* out = (float*)d_out;
    char* ws = (char*)d_ws;

    bf16*  Wt_qkv  = (bf16*)(ws + 0);          // [2304][768]
    bf16*  Wt_proj = (bf16*)(ws + 3538944);    // [768][768]
    bf16*  Wt_fc1  = (bf16*)(ws + 4718592);    // [3072][768]
    bf16*  Wt_fc2  = (bf16*)(ws + 9437184);    // [768][3072]
    bf16*  hbuf    = (bf16*)(ws + 14155776);   // [8192][768]
    bf16*  qkvbuf  = (bf16*)(ws + 26738688);   // [8192][2304]
    bf16*  attnout = (bf16*)(ws + 64487424);   // [8192][768]
    float* x1      = (float*)(ws + 77070336);  // [8192][768]
    bf16*  h2      = (bf16*)(ws + 102236160);  // [8192][768]
    bf16*  a1      = (bf16*)(ws + 114819072);  // [8192][3072] (FC1 out)
    // Q/K/Vt overlay a1's region: used only during attention, before FC1.
    bf16*  Qb      = (bf16*)(ws + 114819072);  // [4][12][2048][64]
    bf16*  Kb      = (bf16*)(ws + 127401984);
    bf16*  Vt      = (bf16*)(ws + 139984896);

    const dim3 tb(32, 8);
    transpose_bf16<<<dim3(2304 / 32, 768 / 32), tb, 0, stream>>>(qkv_w, Wt_qkv, 768, 2304);
    transpose_bf16<<<dim3(768 / 32, 768 / 32), tb, 0, stream>>>(proj_w, Wt_proj, 768, 768);
    transpose_bf16<<<dim3(3072 / 32, 768 / 32), tb, 0, stream>>>(fc1_w, Wt_fc1, 768, 3072);
    transpose_bf16<<<dim3(768 / 32, 3072 / 32), tb, 0, stream>>>(fc2_w, Wt_fc2, 3072, 768);

    ln_kernel<<<8192, 256, 0, stream>>>(x, ln1_g, ln1_b, hbuf);
    gemm_bt<0><<<dim3(64, 18), 256, 0, stream>>>(hbuf, Wt_qkv, qkv_b, nullptr, qkvbuf, 8192, 2304, 768);
    qkv_rearrange<<<dim3(32, 12, 4), 256, 0, stream>>>(qkvbuf, Qb, Kb, Vt);
    attn_kernel<<<dim3(32, 12, 4), 256, 0, stream>>>(Qb, Kb, Vt, mask, attnout);
    gemm_bt<1><<<dim3(64, 6), 256, 0, stream>>>(attnout, Wt_proj, proj_b, x, x1, 8192, 768, 768);
    ln_kernel<<<8192, 256, 0, stream>>>(x1, ln2_g, ln2_b, h2);
    gemm_bt<2><<<dim3(64, 24), 256, 0, stream>>>(h2, Wt_fc1, fc1_b, nullptr, a1, 8192, 3072, 768);
    gemm_bt<1><<<dim3(64, 6), 256, 0, stream>>>(a1, Wt_fc2, fc2_b, x1, out, 8192, 768, 3072);
}

// Round 3
// 310.701 us; speedup vs baseline: 1.2927x; 1.2369x over previous
//
#include <hip/hip_runtime.h>
#include <hip/hip_bf16.h>
#include <math.h>

using bf16 = __hip_bfloat16;
typedef short s16x8 __attribute__((ext_vector_type(8)));
typedef float f32x4 __attribute__((ext_vector_type(4)));
typedef float f32x16 __attribute__((ext_vector_type(16)));

__device__ inline unsigned short f2bf(float f) {
    bf16 h = __float2bfloat16(f);
    return __builtin_bit_cast(unsigned short, h);
}

// async global->LDS, 16B per lane. Dest must be wave-linear (base + lane*16).
__device__ inline void gload_lds16(const void* g, void* l) {
    __builtin_amdgcn_global_load_lds(
        (const __attribute__((address_space(1))) void*)g,
        (__attribute__((address_space(3))) void*)l, 16, 0, 0);
}

// value of the partner half (lane^32) without LDS: one permlane32_swap + cndmask
__device__ inline float swap_halves(float x, int hi) {
    unsigned a = __builtin_bit_cast(unsigned, x);
    unsigned b = a;
    asm volatile("v_permlane32_swap_b32 %0, %1" : "+v"(a), "+v"(b));
    // lanes<32: partner value is in b; lanes>=32: in a
    return hi ? __builtin_bit_cast(float, a) : __builtin_bit_cast(float, b);
}

__device__ inline unsigned cvtpk(float lo, float hi) {
    unsigned r;
    asm("v_cvt_pk_bf16_f32 %0, %1, %2" : "=v"(r) : "v"(lo), "v"(hi));
    return r;
}

// Build PV B-operand fragment (keys base+0..15 for this lane's half) from
// 8 in-lane P values p[0..7] (keys 4*hi + {0,1,2,3, 8,9,10,11} of the 16).
// After cvt_pk + permlane32_swap each lane holds keys 8*hi + 0..7 packed bf16x8.
__device__ inline s16x8 build_pfrag(float p0, float p1, float p2, float p3,
                                    float p4, float p5, float p6, float p7) {
    unsigned w01 = cvtpk(p0, p1);
    unsigned w23 = cvtpk(p2, p3);
    unsigned w45 = cvtpk(p4, p5);
    unsigned w67 = cvtpk(p6, p7);
    asm volatile("v_permlane32_swap_b32 %0, %1" : "+v"(w01), "+v"(w45));
    asm volatile("v_permlane32_swap_b32 %0, %1" : "+v"(w23), "+v"(w67));
    int4 t = {(int)w01, (int)w23, (int)w45, (int)w67};
    return __builtin_bit_cast(s16x8, t);
}

// ---------------------------------------------------------------------------
// Weight prep: in [K][N] fp32 row-major  ->  out [N][K] bf16 row-major (W^T)
// ---------------------------------------------------------------------------
__global__ __launch_bounds__(256) void transpose_bf16(
    const float* __restrict__ in, bf16* __restrict__ out, int K, int N)
{
    __shared__ float tile[32][33];
    const int bx = blockIdx.x * 32;  // n
    const int by = blockIdx.y * 32;  // k
    const int tx = threadIdx.x, ty = threadIdx.y;  // 32 x 8
    #pragma unroll
    for (int i = 0; i < 32; i += 8)
        tile[ty + i][tx] = in[(size_t)(by + ty + i) * N + bx + tx];
    __syncthreads();
    #pragma unroll
    for (int i = 0; i < 32; i += 8)
        out[(size_t)(bx + ty + i) * K + by + tx] = __float2bfloat16(tile[tx][ty + i]);
}

// ---------------------------------------------------------------------------
// LayerNorm over C=768, fp32 in -> bf16 out. One 256-thread block per row.
// ---------------------------------------------------------------------------
__global__ __launch_bounds__(256) void ln_kernel(
    const float* __restrict__ x, const float* __restrict__ g,
    const float* __restrict__ bb, bf16* __restrict__ out)
{
    const int row = blockIdx.x;
    const float* xr = x + (size_t)row * 768;
    float v[3];
    float s = 0.f, s2 = 0.f;
    #pragma unroll
    for (int i = 0; i < 3; ++i) {
        v[i] = xr[threadIdx.x + i * 256];
        s += v[i];
        s2 += v[i] * v[i];
    }
    #pragma unroll
    for (int off = 1; off < 64; off <<= 1) {
        s += __shfl_xor(s, off);
        s2 += __shfl_xor(s2, off);
    }
    __shared__ float rs[4], rs2[4];
    const int wave = threadIdx.x >> 6;
    if ((threadIdx.x & 63) == 0) { rs[wave] = s; rs2[wave] = s2; }
    __syncthreads();
    s = rs[0] + rs[1] + rs[2] + rs[3];
    s2 = rs2[0] + rs2[1] + rs2[2] + rs2[3];
    const float mu = s * (1.f / 768.f);
    const float var = s2 * (1.f / 768.f) - mu * mu;
    const float r = rsqrtf(var + 1e-6f);
    bf16* orow = out + (size_t)row * 768;
    #pragma unroll
    for (int i = 0; i < 3; ++i) {
        const int col = threadIdx.x + i * 256;
        orow[col] = __float2bfloat16((v[i] - mu) * r * g[col] + bb[col]);
    }
}

// ---------------------------------------------------------------------------
// QKV rearrange: qkv [B*N][2304] -> Qb [B][H][N][D] (pre-scaled by D^-0.5),
// Kb [B][H][N][D], Vt [B][H][D][N]. All coalesced; V transposed via LDS.
// ---------------------------------------------------------------------------
__global__ __launch_bounds__(256) void qkv_rearrange(
    const bf16* __restrict__ qkv, bf16* __restrict__ Qb,
    bf16* __restrict__ Kb, bf16* __restrict__ Vt)
{
    const int nt = blockIdx.x, h = blockIdx.y, b = blockIdx.z;
    const int tid = threadIdx.x;
    const size_t bh = (size_t)(b * 12 + h);
    const int n0 = nt * 64;

    __shared__ unsigned short vtile[64][65];

    #pragma unroll
    for (int i = 0; i < 2; ++i) {
        const int id = tid + i * 256;
        const int row = id >> 3, c = id & 7;
        const size_t src = (size_t)(b * 2048 + n0 + row) * 2304 + h * 64 + c * 8;
        unsigned short tq[8];
        *reinterpret_cast<int4*>(tq) = *reinterpret_cast<const int4*>(qkv + src);
        #pragma unroll
        for (int j = 0; j < 8; ++j)
            tq[j] = f2bf(__bfloat162float(__builtin_bit_cast(bf16, tq[j])) * 0.125f);
        *reinterpret_cast<int4*>(Qb + (bh * 2048 + n0 + row) * 64 + c * 8) =
            *reinterpret_cast<const int4*>(tq);
        *reinterpret_cast<int4*>(Kb + (bh * 2048 + n0 + row) * 64 + c * 8) =
            *reinterpret_cast<const int4*>(qkv + src + 768);
        unsigned short tv[8];
        *reinterpret_cast<int4*>(tv) = *reinterpret_cast<const int4*>(qkv + src + 1536);
        #pragma unroll
        for (int j = 0; j < 8; ++j) vtile[row][c * 8 + j] = tv[j];
    }
    __syncthreads();
    #pragma unroll
    for (int i = 0; i < 2; ++i) {
        const int id = tid + i * 256;
        const int d = id >> 3, c = id & 7;
        unsigned short tmp[8];
        #pragma unroll
        for (int j = 0; j < 8; ++j) tmp[j] = vtile[c * 8 + j][d];
        *reinterpret_cast<int4*>(Vt + (bh * 64 + d) * 2048 + n0 + c * 8) =
            *reinterpret_cast<const int4*>(tmp);
    }
}

// ---------------------------------------------------------------------------
// GEMM: out[M][N] = A[M][K] @ Bt[N][K]^T + bias (+ residual / gelu)
// ---------------------------------------------------------------------------
#define BM 128
#define BN 128
#define BK 64

template <int EPI>
__global__ __launch_bounds__(256) void gemm_bt(
    const bf16* __restrict__ A, const bf16* __restrict__ Bt,
    const float* __restrict__ bias, const float* __restrict__ resid,
    void* __restrict__ outp, int M, int N, int K)
{
    __shared__ alignas(16) char As[BM * BK * 2];
    __shared__ alignas(16) char Bs[BN * BK * 2];
    const int tid = threadIdx.x;
    const int lane = tid & 63;
    const int wave = tid >> 6;
    const int wm = wave >> 1, wn = wave & 1;
    const int lr = lane & 15, lg = lane >> 4;
    const int bm = blockIdx.x, bn = blockIdx.y;

    f32x4 acc[4][4] = {};

    const size_t a_row0 = (size_t)bm * BM;
    const size_t b_row0 = (size_t)bn * BN;

    for (int kt = 0; kt < K; kt += BK) {
        #pragma unroll
        for (int i = 0; i < 4; ++i) {
            const int id = tid + i * 256;
            const int row = id >> 3, c = id & 7;
            const int cs = (c ^ (row & 7)) * 8;  // inverse swizzle on source
            gload_lds16(A + (a_row0 + row) * K + kt + cs, As + id * 16);
            gload_lds16(Bt + (b_row0 + row) * K + kt + cs, Bs + id * 16);
        }
        __syncthreads();
        #pragma unroll
        for (int ks = 0; ks < 2; ++ks) {
            s16x8 af[4], bfr[4];
            #pragma unroll
            for (int mf = 0; mf < 4; ++mf) {
                const int row = wm * 64 + mf * 16 + lr;
                const int c = ks * 4 + lg;
                af[mf] = *reinterpret_cast<const s16x8*>(As + row * 128 + ((c ^ (row & 7)) * 16));
            }
            #pragma unroll
            for (int nf = 0; nf < 4; ++nf) {
                const int row = wn * 64 + nf * 16 + lr;
                const int c = ks * 4 + lg;
                bfr[nf] = *reinterpret_cast<const s16x8*>(Bs + row * 128 + ((c ^ (row & 7)) * 16));
            }
            #pragma unroll
            for (int mf = 0; mf < 4; ++mf)
                #pragma unroll
                for (int nf = 0; nf < 4; ++nf)
                    acc[mf][nf] = __builtin_amdgcn_mfma_f32_16x16x32_bf16(
                        af[mf], bfr[nf], acc[mf][nf], 0, 0, 0);
        }
        __syncthreads();
    }

    #pragma unroll
    for (int mf = 0; mf < 4; ++mf) {
        #pragma unroll
        for (int i = 0; i < 4; ++i) {
            const int gm = bm * BM + wm * 64 + mf * 16 + 4 * lg + i;
            #pragma unroll
            for (int nf = 0; nf < 4; ++nf) {
                const int gn = bn * BN + wn * 64 + nf * 16 + lr;
                float v = acc[mf][nf][i] + bias[gn];
                if (EPI == 1) v += resid[(size_t)gm * N + gn];
                if (EPI == 2) v = 0.5f * v * (1.0f + erff(v * 0.70710678118654752f));
                if (EPI == 1)
                    reinterpret_cast<float*>(outp)[(size_t)gm * N + gn] = v;
                else
                    reinterpret_cast<bf16*>(outp)[(size_t)gm * N + gn] = __float2bfloat16(v);
            }
        }
    }
}

// ---------------------------------------------------------------------------
// Flash attention, swapped-QK^T in-register-softmax structure (m214 port).
// Qb/Kb [B][H][N][64] (Q pre-scaled), Vt [B][H][64][N], bf16.
// Grid (16 qblocks, 12 h, 4 b) x 256 thr = 4 waves; each wave owns 32 q-rows.
// Per 64-key KV tile: stage K[64][64] + V^T[64][64] in LDS (swizzled), then
// 2 subtiles of 32 keys: S^T = mfma32x32(K, Q) -> lane holds 16 of 32 keys
// for q = lane&31; softmax in-register; P^T B-frags via cvt_pk+permlane32;
// O^T += mfma32x32(V^T, P^T) -> per-q stats stay lane-local.
// ---------------------------------------------------------------------------
__global__ __launch_bounds__(256, 3) void attn_kernel(
    const bf16* __restrict__ Qb, const bf16* __restrict__ Kb,
    const bf16* __restrict__ Vt, const int* __restrict__ mask,
    bf16* __restrict__ out)
{
    __shared__ alignas(16) char Ks[64 * 128];   // [key][d]  swizzled, 8KB
    __shared__ alignas(16) char Vs[64 * 128];   // [d][key]  swizzled, 8KB

    const int qb = blockIdx.x, h = blockIdx.y, b = blockIdx.z;
    const int tid = threadIdx.x, lane = tid & 63, wave = tid >> 6;
    const int lq = lane & 31;        // this lane's q-column / A-row index
    const int hi = lane >> 5;
    const size_t bh = (size_t)(b * 12 + h);
    const bf16* Kh = Kb + bh * 2048 * 64;
    const bf16* Vh = Vt + bh * 64 * 2048;
    const int q0w = qb * 128 + wave * 32;

    // Q fragments: qf[ks] covers d = 16*ks + 8*hi + j   (B-operand layout)
    s16x8 qf[4];
    {
        const bf16* qp = Qb + (bh * 2048 + q0w + lq) * 64 + 8 * hi;
        #pragma unroll
        for (int ks = 0; ks < 4; ++ks)
            qf[ks] = *reinterpret_cast<const s16x8*>(qp + 16 * ks);
    }
    const int mrow = mask[b * 2048 + q0w + lq];

    float m_r = -1e30f, l_r = 0.f;
    f32x16 o0 = {}, o1 = {};   // O^T accumulators: d 0..31 / 32..63, col=q

    for (int kb = 0; kb < 32; ++kb) {
        // ---- stage K tile [64 key][64 d] and V^T tile [64 d][64 key] ----
        #pragma unroll
        for (int i = 0; i < 2; ++i) {
            const int id = tid + i * 256;
            const int row = id >> 3, c = id & 7;
            const int cs = (c ^ (row & 7)) * 8;
            gload_lds16(Kh + (size_t)(kb * 64 + row) * 64 + cs, Ks + id * 16);
            gload_lds16(Vh + (size_t)row * 2048 + kb * 64 + cs, Vs + id * 16);
        }
        __syncthreads();

        #pragma unroll
        for (int sub = 0; sub < 2; ++sub) {
            // ---- S^T[key][q] over 32 keys: 4 MFMAs (K-dim = d = 64) ----
            f32x16 st = {};
            __builtin_amdgcn_s_setprio(1);
            #pragma unroll
            for (int ks = 0; ks < 4; ++ks) {
                const int row = sub * 32 + lq;           // key row in tile
                const int c8 = 2 * ks + hi;
                const s16x8 kf = *reinterpret_cast<const s16x8*>(
                    Ks + row * 128 + ((c8 ^ (row & 7)) * 16));
                st = __builtin_amdgcn_mfma_f32_32x32x16_bf16(kf, qf[ks], st, 0, 0, 0);
            }
            __builtin_amdgcn_s_setprio(0);

            // ---- in-register softmax (lane holds 16 of 32 keys for its q) ----
            float p[16];
            #pragma unroll
            for (int r = 0; r < 16; ++r) p[r] = mrow ? st[r] : 0.f;
            float mx = p[0];
            #pragma unroll
            for (int r = 1; r < 16; ++r) mx = fmaxf(mx, p[r]);
            mx = fmaxf(mx, swap_halves(mx, hi));
            const float mnew = fmaxf(m_r, mx);
            const float alpha = __expf(m_r - mnew);
            m_r = mnew;
            float rs = 0.f;
            #pragma unroll
            for (int r = 0; r < 16; ++r) {
                p[r] = __expf(p[r] - mnew);
                rs += p[r];
            }
            rs += swap_halves(rs, hi);
            l_r = l_r * alpha + rs;
            #pragma unroll
            for (int r = 0; r < 16; ++r) { o0[r] *= alpha; o1[r] *= alpha; }

            // ---- build P^T B-frags (2 x 16 keys) ----
            const s16x8 pf0 = build_pfrag(p[0], p[1], p[2], p[3], p[4], p[5], p[6], p[7]);
            const s16x8 pf1 = build_pfrag(p[8], p[9], p[10], p[11], p[12], p[13], p[14], p[15]);

            // ---- O^T += V^T * P^T : 2 d-halves x 2 key-frags ----
            __builtin_amdgcn_s_setprio(1);
            #pragma unroll
            for (int ks2 = 0; ks2 < 2; ++ks2) {
                const s16x8 pf = ks2 ? pf1 : pf0;
                const int c8 = 4 * sub + 2 * ks2 + hi;
                {
                    const int row = lq;                   // d 0..31
                    const s16x8 vf = *reinterpret_cast<const s16x8*>(
                        Vs + row * 128 + ((c8 ^ (row & 7)) * 16));
                    o0 = __builtin_amdgcn_mfma_f32_32x32x16_bf16(vf, pf, o0, 0, 0, 0);
                }
                {
                    const int row = 32 + lq;              // d 32..63
                    const s16x8 vf = *reinterpret_cast<const s16x8*>(
                        Vs + row * 128 + ((c8 ^ (row & 7)) * 16));
                    o1 = __builtin_amdgcn_mfma_f32_32x32x16_bf16(vf, pf, o1, 0, 0, 0);
                }
            }
            __builtin_amdgcn_s_setprio(0);
        }
        __syncthreads();
    }

    // ---- epilogue: normalize and store transposed (O^T[d][q] -> out[q][d]) ----
    const float rl = 1.0f / l_r;
    bf16* orow = out + (size_t)(b * 2048 + q0w + lq) * 768 + h * 64;
    #pragma unroll
    for (int g = 0; g < 4; ++g) {
        unsigned short pk0[4], pk1[4];
        #pragma unroll
        for (int i = 0; i < 4; ++i) {
            pk0[i] = f2bf(o0[4 * g + i] * rl);
            pk1[i] = f2bf(o1[4 * g + i] * rl);
        }
        const int d0 = 8 * g + 4 * hi;
        *reinterpret_cast<int2*>(orow + d0) = *reinterpret_cast<const int2*>(pk0);
        *reinterpret_cast<int2*>(orow + 32 + d0) = *reinterpret_cast<const int2*>(pk1);
    }
}

// ---------------------------------------------------------------------------
// Launch
// ---------------------------------------------------------------------------
extern "C" void kernel_launch(void* const* d_in, const int* in_sizes, int n_in,
                              void* d_out, int out_size, void* d_ws, size_t ws_size,
                              hipStream_t stream)
{
    (void)in_sizes; (void)n_in; (void)out_size; (void)ws_size;
    const float* x      = (const float*)d_in[0];
    const int*   mask   = (const int*)d_in[1];
    const float* ln1_g  = (const float*)d_in[2];
    const float* ln1_b  = (const float*)d_in[3];
    const float* qkv_w  = (const float*)d_in[4];
    const float* qkv_b  = (const float*)d_in[5];
    const float* proj_w = (const float*)d_in[6];
    const float* proj_b = (const float*)d_in[7];
    const float* ln2_g  = (const float*)d_in[8];
    const float* ln2_b  = (const float*)d_in[9];
    const float* fc1_w  = (const float*)d_in[10];
    const float* fc1_b  = (const float*)d_in[11];
    const float* fc2_w  = (const float*)d_in[12];
    const float* fc2_b  = (const float*)d_in[13];
    float* out = (float*)d_out;
    char* ws = (char*)d_ws;

    bf16*  Wt_qkv  = (bf16*)(ws + 0);          // [2304][768]
    bf16*  Wt_proj = (bf16*)(ws + 3538944);    // [768][768]
    bf16*  Wt_fc1  = (bf16*)(ws + 4718592);    // [3072][768]
    bf16*  Wt_fc2  = (bf16*)(ws + 9437184);    // [768][3072]
    bf16*  hbuf    = (bf16*)(ws + 14155776);   // [8192][768]
    bf16*  qkvbuf  = (bf16*)(ws + 26738688);   // [8192][2304]
    bf16*  attnout = (bf16*)(ws + 64487424);   // [8192][768]
    float* x1      = (float*)(ws + 77070336);  // [8192][768]
    bf16*  h2      = (bf16*)(ws + 102236160);  // [8192][768]
    bf16*  a1      = (bf16*)(ws + 114819072);  // [8192][3072] (FC1 out)
    bf16*  Qb      = (bf16*)(ws + 114819072);  // overlay: [4][12][2048][64]
    bf16*  Kb      = (bf16*)(ws + 127401984);
    bf16*  Vt      = (bf16*)(ws + 139984896);

    const dim3 tb(32, 8);
    transpose_bf16<<<dim3(2304 / 32, 768 / 32), tb, 0, stream>>>(qkv_w, Wt_qkv, 768, 2304);
    transpose_bf16<<<dim3(768 / 32, 768 / 32), tb, 0, stream>>>(proj_w, Wt_proj, 768, 768);
    transpose_bf16<<<dim3(3072 / 32, 768 / 32), tb, 0, stream>>>(fc1_w, Wt_fc1, 768, 3072);
    transpose_bf16<<<dim3(768 / 32, 3072 / 32), tb, 0, stream>>>(fc2_w, Wt_fc2, 3072, 768);

    ln_kernel<<<8192, 256, 0, stream>>>(x, ln1_g, ln1_b, hbuf);
    gemm_bt<0><<<dim3(64, 18), 256, 0, stream>>>(hbuf, Wt_qkv, qkv_b, nullptr, qkvbuf, 8192, 2304, 768);
    qkv_rearrange<<<dim3(32, 12, 4), 256, 0, stream>>>(qkvbuf, Qb, Kb, Vt);
    attn_kernel<<<dim3(16, 12, 4), 256, 0, stream>>>(Qb, Kb, Vt, mask, attnout);
    gemm_bt<1><<<dim3(64, 6), 256, 0, stream>>>(attnout, Wt_proj, proj_b, x, x1, 8192, 768, 768);
    ln_kernel<<<8192, 256, 0, stream>>>(x1, ln2_g, ln2_b, h2);
    gemm_bt<2><<<dim3(64, 24), 256, 0, stream>>>(h2, Wt_fc1, fc1_b, nullptr, a1, 8192, 3072, 768);
    gemm_bt<1><<<dim3(64, 6), 256, 0, stream>>>(a1, Wt_fc2, fc2_b, x1, out, 8192, 768, 3072);
}

// Round 4
// 299.831 us; speedup vs baseline: 1.3395x; 1.0363x over previous
//
#include <hip/hip_runtime.h>
#include <hip/hip_bf16.h>
#include <math.h>

using bf16 = __hip_bfloat16;
typedef short s16x8 __attribute__((ext_vector_type(8)));
typedef float f32x4 __attribute__((ext_vector_type(4)));
typedef float f32x16 __attribute__((ext_vector_type(16)));

#define LOG2E 1.4426950408889634f

__device__ inline unsigned short f2bf(float f) {
    bf16 h = __float2bfloat16(f);
    return __builtin_bit_cast(unsigned short, h);
}

// async global->LDS, 16B per lane. Dest must be wave-linear (base + lane*16).
__device__ inline void gload_lds16(const void* g, void* l) {
    __builtin_amdgcn_global_load_lds(
        (const __attribute__((address_space(1))) void*)g,
        (__attribute__((address_space(3))) void*)l, 16, 0, 0);
}

// value of the partner half (lane^32) without LDS: one permlane32_swap
__device__ inline float swap_halves(float x, int hi) {
    unsigned a = __builtin_bit_cast(unsigned, x);
    unsigned b = a;
    asm volatile("v_permlane32_swap_b32 %0, %1" : "+v"(a), "+v"(b));
    return hi ? __builtin_bit_cast(float, a) : __builtin_bit_cast(float, b);
}

__device__ inline unsigned cvtpk(float lo, float hi) {
    unsigned r;
    asm("v_cvt_pk_bf16_f32 %0, %1, %2" : "=v"(r) : "v"(lo), "v"(hi));
    return r;
}

// Build PV B-operand fragment from 8 in-lane P values (same mapping as R3,
// verified passing): after cvt_pk + permlane32_swap each lane holds its
// half's 8 keys packed bf16x8.
__device__ inline s16x8 build_pfrag(float p0, float p1, float p2, float p3,
                                    float p4, float p5, float p6, float p7) {
    unsigned w01 = cvtpk(p0, p1);
    unsigned w23 = cvtpk(p2, p3);
    unsigned w45 = cvtpk(p4, p5);
    unsigned w67 = cvtpk(p6, p7);
    asm volatile("v_permlane32_swap_b32 %0, %1" : "+v"(w01), "+v"(w45));
    asm volatile("v_permlane32_swap_b32 %0, %1" : "+v"(w23), "+v"(w67));
    int4 t = {(int)w01, (int)w23, (int)w45, (int)w67};
    return __builtin_bit_cast(s16x8, t);
}

// ---------------------------------------------------------------------------
// Weight prep: in [K][N] fp32 row-major  ->  out [N][K] bf16 row-major (W^T)
// ---------------------------------------------------------------------------
__global__ __launch_bounds__(256) void transpose_bf16(
    const float* __restrict__ in, bf16* __restrict__ out, int K, int N)
{
    __shared__ float tile[32][33];
    const int bx = blockIdx.x * 32;  // n
    const int by = blockIdx.y * 32;  // k
    const int tx = threadIdx.x, ty = threadIdx.y;  // 32 x 8
    #pragma unroll
    for (int i = 0; i < 32; i += 8)
        tile[ty + i][tx] = in[(size_t)(by + ty + i) * N + bx + tx];
    __syncthreads();
    #pragma unroll
    for (int i = 0; i < 32; i += 8)
        out[(size_t)(bx + ty + i) * K + by + tx] = __float2bfloat16(tile[tx][ty + i]);
}

// ---------------------------------------------------------------------------
// LayerNorm over C=768, fp32 in -> bf16 out. One 256-thread block per row.
// ---------------------------------------------------------------------------
__global__ __launch_bounds__(256) void ln_kernel(
    const float* __restrict__ x, const float* __restrict__ g,
    const float* __restrict__ bb, bf16* __restrict__ out)
{
    const int row = blockIdx.x;
    const float* xr = x + (size_t)row * 768;
    float v[3];
    float s = 0.f, s2 = 0.f;
    #pragma unroll
    for (int i = 0; i < 3; ++i) {
        v[i] = xr[threadIdx.x + i * 256];
        s += v[i];
        s2 += v[i] * v[i];
    }
    #pragma unroll
    for (int off = 1; off < 64; off <<= 1) {
        s += __shfl_xor(s, off);
        s2 += __shfl_xor(s2, off);
    }
    __shared__ float rs[4], rs2[4];
    const int wave = threadIdx.x >> 6;
    if ((threadIdx.x & 63) == 0) { rs[wave] = s; rs2[wave] = s2; }
    __syncthreads();
    s = rs[0] + rs[1] + rs[2] + rs[3];
    s2 = rs2[0] + rs2[1] + rs2[2] + rs2[3];
    const float mu = s * (1.f / 768.f);
    const float var = s2 * (1.f / 768.f) - mu * mu;
    const float r = rsqrtf(var + 1e-6f);
    bf16* orow = out + (size_t)row * 768;
    #pragma unroll
    for (int i = 0; i < 3; ++i) {
        const int col = threadIdx.x + i * 256;
        orow[col] = __float2bfloat16((v[i] - mu) * r * g[col] + bb[col]);
    }
}

// ---------------------------------------------------------------------------
// QKV rearrange: qkv [B*N][2304] -> Qb [B][H][N][D] (pre-scaled by D^-0.5,
// zeroed where mask==0: scores all-0 == reference's whole-row mask ->
// uniform softmax), Kb [B][H][N][D], Vt [B][H][D][N].
// ---------------------------------------------------------------------------
__global__ __launch_bounds__(256) void qkv_rearrange(
    const bf16* __restrict__ qkv, const int* __restrict__ mask,
    bf16* __restrict__ Qb, bf16* __restrict__ Kb, bf16* __restrict__ Vt)
{
    const int nt = blockIdx.x, h = blockIdx.y, b = blockIdx.z;
    const int tid = threadIdx.x;
    const size_t bh = (size_t)(b * 12 + h);
    const int n0 = nt * 64;

    __shared__ unsigned short vtile[64][65];

    #pragma unroll
    for (int i = 0; i < 2; ++i) {
        const int id = tid + i * 256;
        const int row = id >> 3, c = id & 7;
        const size_t src = (size_t)(b * 2048 + n0 + row) * 2304 + h * 64 + c * 8;
        const float qs = mask[b * 2048 + n0 + row] ? 0.125f : 0.f;
        unsigned short tq[8];
        *reinterpret_cast<int4*>(tq) = *reinterpret_cast<const int4*>(qkv + src);
        #pragma unroll
        for (int j = 0; j < 8; ++j)
            tq[j] = f2bf(__bfloat162float(__builtin_bit_cast(bf16, tq[j])) * qs);
        *reinterpret_cast<int4*>(Qb + (bh * 2048 + n0 + row) * 64 + c * 8) =
            *reinterpret_cast<const int4*>(tq);
        *reinterpret_cast<int4*>(Kb + (bh * 2048 + n0 + row) * 64 + c * 8) =
            *reinterpret_cast<const int4*>(qkv + src + 768);
        unsigned short tv[8];
        *reinterpret_cast<int4*>(tv) = *reinterpret_cast<const int4*>(qkv + src + 1536);
        #pragma unroll
        for (int j = 0; j < 8; ++j) vtile[row][c * 8 + j] = tv[j];
    }
    __syncthreads();
    #pragma unroll
    for (int i = 0; i < 2; ++i) {
        const int id = tid + i * 256;
        const int d = id >> 3, c = id & 7;
        unsigned short tmp[8];
        #pragma unroll
        for (int j = 0; j < 8; ++j) tmp[j] = vtile[c * 8 + j][d];
        *reinterpret_cast<int4*>(Vt + (bh * 64 + d) * 2048 + n0 + c * 8) =
            *reinterpret_cast<const int4*>(tmp);
    }
}

// ---------------------------------------------------------------------------
// GEMM: out[M][N] = A[M][K] @ Bt[N][K]^T + bias (+ residual / gelu)
// ---------------------------------------------------------------------------
#define BM 128
#define BN 128
#define BK 64

template <int EPI>
__global__ __launch_bounds__(256) void gemm_bt(
    const bf16* __restrict__ A, const bf16* __restrict__ Bt,
    const float* __restrict__ bias, const float* __restrict__ resid,
    void* __restrict__ outp, int M, int N, int K)
{
    __shared__ alignas(16) char As[BM * BK * 2];
    __shared__ alignas(16) char Bs[BN * BK * 2];
    const int tid = threadIdx.x;
    const int lane = tid & 63;
    const int wave = tid >> 6;
    const int wm = wave >> 1, wn = wave & 1;
    const int lr = lane & 15, lg = lane >> 4;
    const int bm = blockIdx.x, bn = blockIdx.y;

    f32x4 acc[4][4] = {};

    const size_t a_row0 = (size_t)bm * BM;
    const size_t b_row0 = (size_t)bn * BN;

    for (int kt = 0; kt < K; kt += BK) {
        #pragma unroll
        for (int i = 0; i < 4; ++i) {
            const int id = tid + i * 256;
            const int row = id >> 3, c = id & 7;
            const int cs = (c ^ (row & 7)) * 8;  // inverse swizzle on source
            gload_lds16(A + (a_row0 + row) * K + kt + cs, As + id * 16);
            gload_lds16(Bt + (b_row0 + row) * K + kt + cs, Bs + id * 16);
        }
        __syncthreads();
        #pragma unroll
        for (int ks = 0; ks < 2; ++ks) {
            s16x8 af[4], bfr[4];
            #pragma unroll
            for (int mf = 0; mf < 4; ++mf) {
                const int row = wm * 64 + mf * 16 + lr;
                const int c = ks * 4 + lg;
                af[mf] = *reinterpret_cast<const s16x8*>(As + row * 128 + ((c ^ (row & 7)) * 16));
            }
            #pragma unroll
            for (int nf = 0; nf < 4; ++nf) {
                const int row = wn * 64 + nf * 16 + lr;
                const int c = ks * 4 + lg;
                bfr[nf] = *reinterpret_cast<const s16x8*>(Bs + row * 128 + ((c ^ (row & 7)) * 16));
            }
            #pragma unroll
            for (int mf = 0; mf < 4; ++mf)
                #pragma unroll
                for (int nf = 0; nf < 4; ++nf)
                    acc[mf][nf] = __builtin_amdgcn_mfma_f32_16x16x32_bf16(
                        af[mf], bfr[nf], acc[mf][nf], 0, 0, 0);
        }
        __syncthreads();
    }

    #pragma unroll
    for (int mf = 0; mf < 4; ++mf) {
        #pragma unroll
        for (int i = 0; i < 4; ++i) {
            const int gm = bm * BM + wm * 64 + mf * 16 + 4 * lg + i;
            #pragma unroll
            for (int nf = 0; nf < 4; ++nf) {
                const int gn = bn * BN + wn * 64 + nf * 16 + lr;
                float v = acc[mf][nf][i] + bias[gn];
                if (EPI == 1) v += resid[(size_t)gm * N + gn];
                if (EPI == 2) v = 0.5f * v * (1.0f + erff(v * 0.70710678118654752f));
                if (EPI == 1)
                    reinterpret_cast<float*>(outp)[(size_t)gm * N + gn] = v;
                else
                    reinterpret_cast<bf16*>(outp)[(size_t)gm * N + gn] = __float2bfloat16(v);
            }
        }
    }
}

// ---------------------------------------------------------------------------
// Flash attention, swapped-QK^T in-register-softmax (m214 port), round 4:
// mask folded into Q; exp2-domain softmax via FMA; defer-max (THR=8);
// double-buffered K/V staging (1 barrier per KV tile).
// ---------------------------------------------------------------------------
__global__ __launch_bounds__(256, 3) void attn_kernel(
    const bf16* __restrict__ Qb, const bf16* __restrict__ Kb,
    const bf16* __restrict__ Vt, bf16* __restrict__ out)
{
    __shared__ alignas(16) char Ks[2][64 * 128];   // [key][d]  swizzled
    __shared__ alignas(16) char Vs[2][64 * 128];   // [d][key]  swizzled

    const int qb = blockIdx.x, h = blockIdx.y, b = blockIdx.z;
    const int tid = threadIdx.x, lane = tid & 63, wave = tid >> 6;
    const int lq = lane & 31;
    const int hi = lane >> 5;
    const size_t bh = (size_t)(b * 12 + h);
    const bf16* Kh = Kb + bh * 2048 * 64;
    const bf16* Vh = Vt + bh * 64 * 2048;
    const int q0w = qb * 128 + wave * 32;

    // Q fragments: qf[ks] covers d = 16*ks + 8*hi + j   (B-operand layout)
    s16x8 qf[4];
    {
        const bf16* qp = Qb + (bh * 2048 + q0w + lq) * 64 + 8 * hi;
        #pragma unroll
        for (int ks = 0; ks < 4; ++ks)
            qf[ks] = *reinterpret_cast<const s16x8*>(qp + 16 * ks);
    }

    float m_r = -1e30f, l_r = 0.f;   // m_r in log2 domain
    f32x16 o0 = {}, o1 = {};         // O^T accumulators: d 0..31 / 32..63

    #define STAGE(buf, kb)                                                        \
        do {                                                                      \
            _Pragma("unroll")                                                     \
            for (int i_ = 0; i_ < 2; ++i_) {                                      \
                const int id_ = tid + i_ * 256;                                   \
                const int row_ = id_ >> 3, c_ = id_ & 7;                          \
                const int cs_ = (c_ ^ (row_ & 7)) * 8;                            \
                gload_lds16(Kh + (size_t)((kb) * 64 + row_) * 64 + cs_,           \
                            Ks[buf] + id_ * 16);                                  \
                gload_lds16(Vh + (size_t)row_ * 2048 + (kb) * 64 + cs_,           \
                            Vs[buf] + id_ * 16);                                  \
            }                                                                     \
        } while (0)

    STAGE(0, 0);
    __syncthreads();
    int cur = 0;

    for (int kb = 0; kb < 32; ++kb) {
        if (kb < 31) STAGE(cur ^ 1, kb + 1);
        const char* Kc = Ks[cur];
        const char* Vc = Vs[cur];

        #pragma unroll
        for (int sub = 0; sub < 2; ++sub) {
            // ---- S^T[key][q] over 32 keys: 4 MFMAs (K-dim = d = 64) ----
            f32x16 st = {};
            __builtin_amdgcn_s_setprio(1);
            #pragma unroll
            for (int ks = 0; ks < 4; ++ks) {
                const int row = sub * 32 + lq;
                const int c8 = 2 * ks + hi;
                const s16x8 kf = *reinterpret_cast<const s16x8*>(
                    Kc + row * 128 + ((c8 ^ (row & 7)) * 16));
                st = __builtin_amdgcn_mfma_f32_32x32x16_bf16(kf, qf[ks], st, 0, 0, 0);
            }
            __builtin_amdgcn_s_setprio(0);

            // ---- in-register softmax, log2 domain, defer-max ----
            float mx = fmaxf(fmaxf(st[0], st[1]), fmaxf(st[2], st[3]));
            float mx2 = fmaxf(fmaxf(st[4], st[5]), fmaxf(st[6], st[7]));
            float mx3 = fmaxf(fmaxf(st[8], st[9]), fmaxf(st[10], st[11]));
            float mx4 = fmaxf(fmaxf(st[12], st[13]), fmaxf(st[14], st[15]));
            mx = fmaxf(fmaxf(mx, mx2), fmaxf(mx3, mx4));
            mx = fmaxf(mx, swap_halves(mx, hi));
            const float ml = mx * LOG2E;
            if (!__all(ml - m_r <= 8.0f)) {
                const float mnew = fmaxf(m_r, ml);
                const float alpha = __builtin_amdgcn_exp2f(m_r - mnew);
                m_r = mnew;
                l_r *= alpha;
                #pragma unroll
                for (int r = 0; r < 16; ++r) { o0[r] *= alpha; o1[r] *= alpha; }
            }
            float p[16];
            float rs = 0.f;
            #pragma unroll
            for (int r = 0; r < 16; ++r) {
                p[r] = __builtin_amdgcn_exp2f(fmaf(st[r], LOG2E, -m_r));
                rs += p[r];
            }
            rs += swap_halves(rs, hi);
            l_r += rs;

            // ---- build P^T B-frags (2 x 16 keys) ----
            const s16x8 pf0 = build_pfrag(p[0], p[1], p[2], p[3], p[4], p[5], p[6], p[7]);
            const s16x8 pf1 = build_pfrag(p[8], p[9], p[10], p[11], p[12], p[13], p[14], p[15]);

            // ---- O^T += V^T * P^T : 2 d-halves x 2 key-frags ----
            __builtin_amdgcn_s_setprio(1);
            #pragma unroll
            for (int ks2 = 0; ks2 < 2; ++ks2) {
                const s16x8 pf = ks2 ? pf1 : pf0;
                const int c8 = 4 * sub + 2 * ks2 + hi;
                {
                    const int row = lq;
                    const s16x8 vf = *reinterpret_cast<const s16x8*>(
                        Vc + row * 128 + ((c8 ^ (row & 7)) * 16));
                    o0 = __builtin_amdgcn_mfma_f32_32x32x16_bf16(vf, pf, o0, 0, 0, 0);
                }
                {
                    const int row = 32 + lq;
                    const s16x8 vf = *reinterpret_cast<const s16x8*>(
                        Vc + row * 128 + ((c8 ^ (row & 7)) * 16));
                    o1 = __builtin_amdgcn_mfma_f32_32x32x16_bf16(vf, pf, o1, 0, 0, 0);
                }
            }
            __builtin_amdgcn_s_setprio(0);
        }
        __syncthreads();
        cur ^= 1;
    }
    #undef STAGE

    // ---- epilogue: normalize and store (O^T[d][q] -> out[q][d]) ----
    const float rl = 1.0f / l_r;
    bf16* orow = out + (size_t)(b * 2048 + q0w + lq) * 768 + h * 64;
    #pragma unroll
    for (int g = 0; g < 4; ++g) {
        unsigned short pk0[4], pk1[4];
        #pragma unroll
        for (int i = 0; i < 4; ++i) {
            pk0[i] = f2bf(o0[4 * g + i] * rl);
            pk1[i] = f2bf(o1[4 * g + i] * rl);
        }
        const int d0 = 8 * g + 4 * hi;
        *reinterpret_cast<int2*>(orow + d0) = *reinterpret_cast<const int2*>(pk0);
        *reinterpret_cast<int2*>(orow + 32 + d0) = *reinterpret_cast<const int2*>(pk1);
    }
}

// ---------------------------------------------------------------------------
// Launch
// ---------------------------------------------------------------------------
extern "C" void kernel_launch(void* const* d_in, const int* in_sizes, int n_in,
                              void* d_out, int out_size, void* d_ws, size_t ws_size,
                              hipStream_t stream)
{
    (void)in_sizes; (void)n_in; (void)out_size; (void)ws_size;
    const float* x      = (const float*)d_in[0];
    const int*   mask   = (const int*)d_in[1];
    const float* ln1_g  = (const float*)d_in[2];
    const float* ln1_b  = (const float*)d_in[3];
    const float* qkv_w  = (const float*)d_in[4];
    const float* qkv_b  = (const float*)d_in[5];
    const float* proj_w = (const float*)d_in[6];
    const float* proj_b = (const float*)d_in[7];
    const float* ln2_g  = (const float*)d_in[8];
    const float* ln2_b  = (const float*)d_in[9];
    const float* fc1_w  = (const float*)d_in[10];
    const float* fc1_b  = (const float*)d_in[11];
    const float* fc2_w  = (const float*)d_in[12];
    const float* fc2_b  = (const float*)d_in[13];
    float* out = (float*)d_out;
    char* ws = (char*)d_ws;

    bf16*  Wt_qkv  = (bf16*)(ws + 0);          // [2304][768]
    bf16*  Wt_proj = (bf16*)(ws + 3538944);    // [768][768]
    bf16*  Wt_fc1  = (bf16*)(ws + 4718592);    // [3072][768]
    bf16*  Wt_fc2  = (bf16*)(ws + 9437184);    // [768][3072]
    bf16*  hbuf    = (bf16*)(ws + 14155776);   // [8192][768]
    bf16*  qkvbuf  = (bf16*)(ws + 26738688);   // [8192][2304]
    bf16*  attnout = (bf16*)(ws + 64487424);   // [8192][768]
    float* x1      = (float*)(ws + 77070336);  // [8192][768]
    bf16*  h2      = (bf16*)(ws + 102236160);  // [8192][768]
    bf16*  a1      = (bf16*)(ws + 114819072);  // [8192][3072] (FC1 out)
    bf16*  Qb      = (bf16*)(ws + 114819072);  // overlay: [4][12][2048][64]
    bf16*  Kb      = (bf16*)(ws + 127401984);
    bf16*  Vt      = (bf16*)(ws + 139984896);

    const dim3 tb(32, 8);
    transpose_bf16<<<dim3(2304 / 32, 768 / 32), tb, 0, stream>>>(qkv_w, Wt_qkv, 768, 2304);
    transpose_bf16<<<dim3(768 / 32, 768 / 32), tb, 0, stream>>>(proj_w, Wt_proj, 768, 768);
    transpose_bf16<<<dim3(3072 / 32, 768 / 32), tb, 0, stream>>>(fc1_w, Wt_fc1, 768, 3072);
    transpose_bf16<<<dim3(768 / 32, 3072 / 32), tb, 0, stream>>>(fc2_w, Wt_fc2, 3072, 768);

    ln_kernel<<<8192, 256, 0, stream>>>(x, ln1_g, ln1_b, hbuf);
    gemm_bt<0><<<dim3(64, 18), 256, 0, stream>>>(hbuf, Wt_qkv, qkv_b, nullptr, qkvbuf, 8192, 2304, 768);
    qkv_rearrange<<<dim3(32, 12, 4), 256, 0, stream>>>(qkvbuf, mask, Qb, Kb, Vt);
    attn_kernel<<<dim3(16, 12, 4), 256, 0, stream>>>(Qb, Kb, Vt, attnout);
    gemm_bt<1><<<dim3(64, 6), 256, 0, stream>>>(attnout, Wt_proj, proj_b, x, x1, 8192, 768, 768);
    ln_kernel<<<8192, 256, 0, stream>>>(x1, ln2_g, ln2_b, h2);
    gemm_bt<2><<<dim3(64, 24), 256, 0, stream>>>(h2, Wt_fc1, fc1_b, nullptr, a1, 8192, 3072, 768);
    gemm_bt<1><<<dim3(64, 6), 256, 0, stream>>>(a1, Wt_fc2, fc2_b, x1, out, 8192, 768, 3072);
}

// Round 5
// 288.527 us; speedup vs baseline: 1.3920x; 1.0392x over previous
//
#include <hip/hip_runtime.h>
#include <hip/hip_bf16.h>
#include <math.h>

using bf16 = __hip_bfloat16;
typedef short s16x8 __attribute__((ext_vector_type(8)));
typedef float f32x4 __attribute__((ext_vector_type(4)));
typedef float f32x16 __attribute__((ext_vector_type(16)));

#define LOG2E 1.4426950408889634f

__device__ inline unsigned short f2bf(float f) {
    bf16 h = __float2bfloat16(f);
    return __builtin_bit_cast(unsigned short, h);
}

// async global->LDS, 16B per lane. Dest must be wave-linear (base + lane*16).
__device__ inline void gload_lds16(const void* g, void* l) {
    __builtin_amdgcn_global_load_lds(
        (const __attribute__((address_space(1))) void*)g,
        (__attribute__((address_space(3))) void*)l, 16, 0, 0);
}

// value of the partner half (lane^32) without LDS: one permlane32_swap
__device__ inline float swap_halves(float x, int hi) {
    unsigned a = __builtin_bit_cast(unsigned, x);
    unsigned b = a;
    asm volatile("v_permlane32_swap_b32 %0, %1" : "+v"(a), "+v"(b));
    return hi ? __builtin_bit_cast(float, a) : __builtin_bit_cast(float, b);
}

__device__ inline unsigned cvtpk(float lo, float hi) {
    unsigned r;
    asm("v_cvt_pk_bf16_f32 %0, %1, %2" : "=v"(r) : "v"(lo), "v"(hi));
    return r;
}

// Build PV B-operand fragment from 8 in-lane P values (verified mapping).
__device__ inline s16x8 build_pfrag(float p0, float p1, float p2, float p3,
                                    float p4, float p5, float p6, float p7) {
    unsigned w01 = cvtpk(p0, p1);
    unsigned w23 = cvtpk(p2, p3);
    unsigned w45 = cvtpk(p4, p5);
    unsigned w67 = cvtpk(p6, p7);
    asm volatile("v_permlane32_swap_b32 %0, %1" : "+v"(w01), "+v"(w45));
    asm volatile("v_permlane32_swap_b32 %0, %1" : "+v"(w23), "+v"(w67));
    int4 t = {(int)w01, (int)w23, (int)w45, (int)w67};
    return __builtin_bit_cast(s16x8, t);
}

// ---------------------------------------------------------------------------
// Weight prep: in [K][N] fp32 row-major  ->  out [N][K] bf16 row-major (W^T)
// ---------------------------------------------------------------------------
__global__ __launch_bounds__(256) void transpose_bf16(
    const float* __restrict__ in, bf16* __restrict__ out, int K, int N)
{
    __shared__ float tile[32][33];
    const int bx = blockIdx.x * 32;  // n
    const int by = blockIdx.y * 32;  // k
    const int tx = threadIdx.x, ty = threadIdx.y;  // 32 x 8
    #pragma unroll
    for (int i = 0; i < 32; i += 8)
        tile[ty + i][tx] = in[(size_t)(by + ty + i) * N + bx + tx];
    __syncthreads();
    #pragma unroll
    for (int i = 0; i < 32; i += 8)
        out[(size_t)(bx + ty + i) * K + by + tx] = __float2bfloat16(tile[tx][ty + i]);
}

// ---------------------------------------------------------------------------
// LayerNorm over C=768, fp32 in -> bf16 out. One 256-thread block per row.
// ---------------------------------------------------------------------------
__global__ __launch_bounds__(256) void ln_kernel(
    const float* __restrict__ x, const float* __restrict__ g,
    const float* __restrict__ bb, bf16* __restrict__ out)
{
    const int row = blockIdx.x;
    const float* xr = x + (size_t)row * 768;
    float v[3];
    float s = 0.f, s2 = 0.f;
    #pragma unroll
    for (int i = 0; i < 3; ++i) {
        v[i] = xr[threadIdx.x + i * 256];
        s += v[i];
        s2 += v[i] * v[i];
    }
    #pragma unroll
    for (int off = 1; off < 64; off <<= 1) {
        s += __shfl_xor(s, off);
        s2 += __shfl_xor(s2, off);
    }
    __shared__ float rs[4], rs2[4];
    const int wave = threadIdx.x >> 6;
    if ((threadIdx.x & 63) == 0) { rs[wave] = s; rs2[wave] = s2; }
    __syncthreads();
    s = rs[0] + rs[1] + rs[2] + rs[3];
    s2 = rs2[0] + rs2[1] + rs2[2] + rs2[3];
    const float mu = s * (1.f / 768.f);
    const float var = s2 * (1.f / 768.f) - mu * mu;
    const float r = rsqrtf(var + 1e-6f);
    bf16* orow = out + (size_t)row * 768;
    #pragma unroll
    for (int i = 0; i < 3; ++i) {
        const int col = threadIdx.x + i * 256;
        orow[col] = __float2bfloat16((v[i] - mu) * r * g[col] + bb[col]);
    }
}

// ---------------------------------------------------------------------------
// GEMM: out[M][N] = A[M][K] @ Bt[N][K]^T + bias (+ residual / gelu)
// EPI: 0 = bias -> bf16 ; 1 = bias+resid -> fp32 ; 2 = bias+gelu -> bf16 ;
//      3 = fused QKV epilogue: scatter to Qb (x0.125, mask-zeroed), Kb, Vt.
// ---------------------------------------------------------------------------
#define BM 128
#define BN 128
#define BK 64

template <int EPI>
__global__ __launch_bounds__(256) void gemm_bt(
    const bf16* __restrict__ A, const bf16* __restrict__ Bt,
    const float* __restrict__ bias, const float* __restrict__ resid,
    void* __restrict__ outp, const int* __restrict__ mask,
    bf16* __restrict__ Qb, bf16* __restrict__ Kb, bf16* __restrict__ Vt,
    int M, int N, int K)
{
    __shared__ alignas(16) char As[BM * BK * 2];
    __shared__ alignas(16) char Bs[BN * BK * 2];
    const int tid = threadIdx.x;
    const int lane = tid & 63;
    const int wave = tid >> 6;
    const int wm = wave >> 1, wn = wave & 1;
    const int lr = lane & 15, lg = lane >> 4;
    const int bm = blockIdx.x, bn = blockIdx.y;

    f32x4 acc[4][4] = {};

    const size_t a_row0 = (size_t)bm * BM;
    const size_t b_row0 = (size_t)bn * BN;

    for (int kt = 0; kt < K; kt += BK) {
        #pragma unroll
        for (int i = 0; i < 4; ++i) {
            const int id = tid + i * 256;
            const int row = id >> 3, c = id & 7;
            const int cs = (c ^ (row & 7)) * 8;  // inverse swizzle on source
            gload_lds16(A + (a_row0 + row) * K + kt + cs, As + id * 16);
            gload_lds16(Bt + (b_row0 + row) * K + kt + cs, Bs + id * 16);
        }
        __syncthreads();
        #pragma unroll
        for (int ks = 0; ks < 2; ++ks) {
            s16x8 af[4], bfr[4];
            #pragma unroll
            for (int mf = 0; mf < 4; ++mf) {
                const int row = wm * 64 + mf * 16 + lr;
                const int c = ks * 4 + lg;
                af[mf] = *reinterpret_cast<const s16x8*>(As + row * 128 + ((c ^ (row & 7)) * 16));
            }
            #pragma unroll
            for (int nf = 0; nf < 4; ++nf) {
                const int row = wn * 64 + nf * 16 + lr;
                const int c = ks * 4 + lg;
                bfr[nf] = *reinterpret_cast<const s16x8*>(Bs + row * 128 + ((c ^ (row & 7)) * 16));
            }
            #pragma unroll
            for (int mf = 0; mf < 4; ++mf)
                #pragma unroll
                for (int nf = 0; nf < 4; ++nf)
                    acc[mf][nf] = __builtin_amdgcn_mfma_f32_16x16x32_bf16(
                        af[mf], bfr[nf], acc[mf][nf], 0, 0, 0);
        }
        __syncthreads();
    }

    if (EPI == 3) {
        // Fused QKV scatter. Each 128-tile spans one batch and one q/k/v region.
        const int rq = bn / 6;                       // 0=q, 1=k, 2=v
        const int bb_ = bm >> 4;                     // batch index
        const int cb = bn * 128 - rq * 768 + wn * 64;  // in-region column base
        if (rq == 2) {
            // V transposed: Vt[(bh*64+d)*2048 + n], 4 tokens packed per store
            #pragma unroll
            for (int nf = 0; nf < 4; ++nf) {
                const int c = cb + nf * 16 + lr;
                const int h = c >> 6, d = c & 63;
                const size_t base = ((size_t)(bb_ * 12 + h) * 64 + d) * 2048;
                const int gn = bn * 128 + wn * 64 + nf * 16 + lr;
                const float bs = bias[gn];
                #pragma unroll
                for (int mf = 0; mf < 4; ++mf) {
                    unsigned short pk[4];
                    #pragma unroll
                    for (int i = 0; i < 4; ++i) pk[i] = f2bf(acc[mf][nf][i] + bs);
                    const int n = (bm * 128 + wm * 64 + mf * 16 + 4 * lg) & 2047;
                    *reinterpret_cast<int2*>(Vt + base + n) =
                        *reinterpret_cast<const int2*>(pk);
                }
            }
        } else {
            bf16* dst = (rq == 0) ? Qb : Kb;
            #pragma unroll
            for (int mf = 0; mf < 4; ++mf) {
                #pragma unroll
                for (int i = 0; i < 4; ++i) {
                    const int gm = bm * 128 + wm * 64 + mf * 16 + 4 * lg + i;
                    const int n = gm & 2047;
                    const float msc = (rq == 0) ? (mask[gm] ? 0.125f : 0.f) : 1.f;
                    #pragma unroll
                    for (int nf = 0; nf < 4; ++nf) {
                        const int c = cb + nf * 16 + lr;
                        const int h = c >> 6, d = c & 63;
                        const int gn = bn * 128 + wn * 64 + nf * 16 + lr;
                        const float v = (acc[mf][nf][i] + bias[gn]) * msc;
                        dst[((size_t)(bb_ * 12 + h) * 2048 + n) * 64 + d] =
                            __float2bfloat16(v);
                    }
                }
            }
        }
        return;
    }

    #pragma unroll
    for (int mf = 0; mf < 4; ++mf) {
        #pragma unroll
        for (int i = 0; i < 4; ++i) {
            const int gm = bm * BM + wm * 64 + mf * 16 + 4 * lg + i;
            #pragma unroll
            for (int nf = 0; nf < 4; ++nf) {
                const int gn = bn * BN + wn * 64 + nf * 16 + lr;
                float v = acc[mf][nf][i] + bias[gn];
                if (EPI == 1) v += resid[(size_t)gm * N + gn];
                if (EPI == 2) v = 0.5f * v * (1.0f + erff(v * 0.70710678118654752f));
                if (EPI == 1)
                    reinterpret_cast<float*>(outp)[(size_t)gm * N + gn] = v;
                else
                    reinterpret_cast<bf16*>(outp)[(size_t)gm * N + gn] = __float2bfloat16(v);
            }
        }
    }
}

// ---------------------------------------------------------------------------
// Flash attention, swapped-QK^T in-register-softmax, round 5:
// joint 64-key softmax (both 32-key subtiles together -> 2x VALU ILP, one
// rescale check + one pair of swap_halves per KV tile), XCD-aware block
// remap (each XCD owns 6 (b,h) pairs -> KV working set 3MB fits its L2).
// ---------------------------------------------------------------------------
__global__ __launch_bounds__(256, 3) void attn_kernel(
    const bf16* __restrict__ Qb, const bf16* __restrict__ Kb,
    const bf16* __restrict__ Vt, bf16* __restrict__ out)
{
    __shared__ alignas(16) char Ks[2][64 * 128];   // [key][d]  swizzled
    __shared__ alignas(16) char Vs[2][64 * 128];   // [d][key]  swizzled

    // bijective XCD remap: lin = qb + 16*(h + 12*b) order replaced by
    // xcd-major so all 16 q-blocks of a (b,h) pair land on one XCD.
    const int lin = blockIdx.x;            // 768 blocks
    const int xcd = lin & 7, slot = lin >> 3;
    const int pair = xcd * 6 + (slot >> 4);   // 0..47
    const int qb = slot & 15;
    const int b = pair / 12, h = pair % 12;

    const int tid = threadIdx.x, lane = tid & 63, wave = tid >> 6;
    const int lq = lane & 31;
    const int hi = lane >> 5;
    const size_t bh = (size_t)(b * 12 + h);
    const bf16* Kh = Kb + bh * 2048 * 64;
    const bf16* Vh = Vt + bh * 64 * 2048;
    const int q0w = qb * 128 + wave * 32;

    // Q fragments: qf[ks] covers d = 16*ks + 8*hi + j   (B-operand layout)
    s16x8 qf[4];
    {
        const bf16* qp = Qb + (bh * 2048 + q0w + lq) * 64 + 8 * hi;
        #pragma unroll
        for (int ks = 0; ks < 4; ++ks)
            qf[ks] = *reinterpret_cast<const s16x8*>(qp + 16 * ks);
    }

    float m_r = -1e30f, l_r = 0.f;   // m_r in log2 domain
    f32x16 o0 = {}, o1 = {};         // O^T accumulators: d 0..31 / 32..63

    #define STAGE(buf, kb)                                                        \
        do {                                                                      \
            _Pragma("unroll")                                                     \
            for (int i_ = 0; i_ < 2; ++i_) {                                      \
                const int id_ = tid + i_ * 256;                                   \
                const int row_ = id_ >> 3, c_ = id_ & 7;                          \
                const int cs_ = (c_ ^ (row_ & 7)) * 8;                            \
                gload_lds16(Kh + (size_t)((kb) * 64 + row_) * 64 + cs_,           \
                            Ks[buf] + id_ * 16);                                  \
                gload_lds16(Vh + (size_t)row_ * 2048 + (kb) * 64 + cs_,           \
                            Vs[buf] + id_ * 16);                                  \
            }                                                                     \
        } while (0)

    STAGE(0, 0);
    __syncthreads();
    int cur = 0;

    for (int kb = 0; kb < 32; ++kb) {
        if (kb < 31) STAGE(cur ^ 1, kb + 1);
        const char* Kc = Ks[cur];
        const char* Vc = Vs[cur];

        // ---- S^T for both 32-key subtiles: 8 MFMAs ----
        f32x16 st0 = {}, st1 = {};
        __builtin_amdgcn_s_setprio(1);
        #pragma unroll
        for (int ks = 0; ks < 4; ++ks) {
            const int row = lq;
            const int c8 = 2 * ks + hi;
            const s16x8 kf = *reinterpret_cast<const s16x8*>(
                Kc + row * 128 + ((c8 ^ (row & 7)) * 16));
            st0 = __builtin_amdgcn_mfma_f32_32x32x16_bf16(kf, qf[ks], st0, 0, 0, 0);
        }
        #pragma unroll
        for (int ks = 0; ks < 4; ++ks) {
            const int row = 32 + lq;
            const int c8 = 2 * ks + hi;
            const s16x8 kf = *reinterpret_cast<const s16x8*>(
                Kc + row * 128 + ((c8 ^ (row & 7)) * 16));
            st1 = __builtin_amdgcn_mfma_f32_32x32x16_bf16(kf, qf[ks], st1, 0, 0, 0);
        }
        __builtin_amdgcn_s_setprio(0);

        // ---- joint softmax over 64 keys, log2 domain, defer-max ----
        float mxa = fmaxf(st0[0], st0[1]), mxb = fmaxf(st1[0], st1[1]);
        #pragma unroll
        for (int r = 2; r < 16; r += 2) {
            mxa = fmaxf(mxa, fmaxf(st0[r], st0[r + 1]));
            mxb = fmaxf(mxb, fmaxf(st1[r], st1[r + 1]));
        }
        float mx = fmaxf(mxa, mxb);
        mx = fmaxf(mx, swap_halves(mx, hi));
        const float ml = mx * LOG2E;
        if (!__all(ml - m_r <= 8.0f)) {
            const float mnew = fmaxf(m_r, ml);
            const float alpha = __builtin_amdgcn_exp2f(m_r - mnew);
            m_r = mnew;
            l_r *= alpha;
            #pragma unroll
            for (int r = 0; r < 16; ++r) { o0[r] *= alpha; o1[r] *= alpha; }
        }
        float p0[16], p1[16];
        float rsa = 0.f, rsb = 0.f;
        #pragma unroll
        for (int r = 0; r < 16; ++r) {
            p0[r] = __builtin_amdgcn_exp2f(fmaf(st0[r], LOG2E, -m_r));
            p1[r] = __builtin_amdgcn_exp2f(fmaf(st1[r], LOG2E, -m_r));
            rsa += p0[r];
            rsb += p1[r];
        }
        float rs = rsa + rsb;
        rs += swap_halves(rs, hi);
        l_r += rs;

        // ---- P^T B-frags (4 x 16 keys) ----
        const s16x8 pf00 = build_pfrag(p0[0], p0[1], p0[2], p0[3], p0[4], p0[5], p0[6], p0[7]);
        const s16x8 pf01 = build_pfrag(p0[8], p0[9], p0[10], p0[11], p0[12], p0[13], p0[14], p0[15]);
        const s16x8 pf10 = build_pfrag(p1[0], p1[1], p1[2], p1[3], p1[4], p1[5], p1[6], p1[7]);
        const s16x8 pf11 = build_pfrag(p1[8], p1[9], p1[10], p1[11], p1[12], p1[13], p1[14], p1[15]);

        // ---- O^T += V^T * P^T : 2 d-halves x 4 key-frags ----
        __builtin_amdgcn_s_setprio(1);
        #pragma unroll
        for (int kf4 = 0; kf4 < 4; ++kf4) {
            const s16x8 pf = (kf4 == 0) ? pf00 : (kf4 == 1) ? pf01
                           : (kf4 == 2) ? pf10 : pf11;
            const int c8 = 2 * kf4 + hi;
            {
                const int row = lq;
                const s16x8 vf = *reinterpret_cast<const s16x8*>(
                    Vc + row * 128 + ((c8 ^ (row & 7)) * 16));
                o0 = __builtin_amdgcn_mfma_f32_32x32x16_bf16(vf, pf, o0, 0, 0, 0);
            }
            {
                const int row = 32 + lq;
                const s16x8 vf = *reinterpret_cast<const s16x8*>(
                    Vc + row * 128 + ((c8 ^ (row & 7)) * 16));
                o1 = __builtin_amdgcn_mfma_f32_32x32x16_bf16(vf, pf, o1, 0, 0, 0);
            }
        }
        __builtin_amdgcn_s_setprio(0);

        __syncthreads();
        cur ^= 1;
    }
    #undef STAGE

    // ---- epilogue: normalize and store (O^T[d][q] -> out[q][d]) ----
    const float rl = 1.0f / l_r;
    bf16* orow = out + (size_t)(b * 2048 + q0w + lq) * 768 + h * 64;
    #pragma unroll
    for (int g = 0; g < 4; ++g) {
        unsigned short pk0[4], pk1[4];
        #pragma unroll
        for (int i = 0; i < 4; ++i) {
            pk0[i] = f2bf(o0[4 * g + i] * rl);
            pk1[i] = f2bf(o1[4 * g + i] * rl);
        }
        const int d0 = 8 * g + 4 * hi;
        *reinterpret_cast<int2*>(orow + d0) = *reinterpret_cast<const int2*>(pk0);
        *reinterpret_cast<int2*>(orow + 32 + d0) = *reinterpret_cast<const int2*>(pk1);
    }
}

// ---------------------------------------------------------------------------
// Launch
// ---------------------------------------------------------------------------
extern "C" void kernel_launch(void* const* d_in, const int* in_sizes, int n_in,
                              void* d_out, int out_size, void* d_ws, size_t ws_size,
                              hipStream_t stream)
{
    (void)in_sizes; (void)n_in; (void)out_size; (void)ws_size;
    const float* x      = (const float*)d_in[0];
    const int*   mask   = (const int*)d_in[1];
    const float* ln1_g  = (const float*)d_in[2];
    const float* ln1_b  = (const float*)d_in[3];
    const float* qkv_w  = (const float*)d_in[4];
    const float* qkv_b  = (const float*)d_in[5];
    const float* proj_w = (const float*)d_in[6];
    const float* proj_b = (const float*)d_in[7];
    const float* ln2_g  = (const float*)d_in[8];
    const float* ln2_b  = (const float*)d_in[9];
    const float* fc1_w  = (const float*)d_in[10];
    const float* fc1_b  = (const float*)d_in[11];
    const float* fc2_w  = (const float*)d_in[12];
    const float* fc2_b  = (const float*)d_in[13];
    float* out = (float*)d_out;
    char* ws = (char*)d_ws;

    bf16*  Wt_qkv  = (bf16*)(ws + 0);          // [2304][768]
    bf16*  Wt_proj = (bf16*)(ws + 3538944);    // [768][768]
    bf16*  Wt_fc1  = (bf16*)(ws + 4718592);    // [3072][768]
    bf16*  Wt_fc2  = (bf16*)(ws + 9437184);    // [768][3072]
    bf16*  hbuf    = (bf16*)(ws + 14155776);   // [8192][768]
    bf16*  attnout = (bf16*)(ws + 64487424);   // [8192][768]
    float* x1      = (float*)(ws + 77070336);  // [8192][768]
    bf16*  h2      = (bf16*)(ws + 102236160);  // [8192][768]
    bf16*  a1      = (bf16*)(ws + 114819072);  // [8192][3072] (FC1 out)
    bf16*  Qb      = (bf16*)(ws + 114819072);  // overlay: [4][12][2048][64]
    bf16*  Kb      = (bf16*)(ws + 127401984);
    bf16*  Vt      = (bf16*)(ws + 139984896);

    const dim3 tb(32, 8);
    transpose_bf16<<<dim3(2304 / 32, 768 / 32), tb, 0, stream>>>(qkv_w, Wt_qkv, 768, 2304);
    transpose_bf16<<<dim3(768 / 32, 768 / 32), tb, 0, stream>>>(proj_w, Wt_proj, 768, 768);
    transpose_bf16<<<dim3(3072 / 32, 768 / 32), tb, 0, stream>>>(fc1_w, Wt_fc1, 768, 3072);
    transpose_bf16<<<dim3(768 / 32, 3072 / 32), tb, 0, stream>>>(fc2_w, Wt_fc2, 3072, 768);

    ln_kernel<<<8192, 256, 0, stream>>>(x, ln1_g, ln1_b, hbuf);
    gemm_bt<3><<<dim3(64, 18), 256, 0, stream>>>(hbuf, Wt_qkv, qkv_b, nullptr, nullptr,
                                                 mask, Qb, Kb, Vt, 8192, 2304, 768);
    attn_kernel<<<768, 256, 0, stream>>>(Qb, Kb, Vt, attnout);
    gemm_bt<1><<<dim3(64, 6), 256, 0, stream>>>(attnout, Wt_proj, proj_b, x, x1,
                                                nullptr, nullptr, nullptr, nullptr, 8192, 768, 768);
    ln_kernel<<<8192, 256, 0, stream>>>(x1, ln2_g, ln2_b, h2);
    gemm_bt<2><<<dim3(64, 24), 256, 0, stream>>>(h2, Wt_fc1, fc1_b, nullptr, a1,
                                                 nullptr, nullptr, nullptr, nullptr, 8192, 3072, 768);
    gemm_bt<1><<<dim3(64, 6), 256, 0, stream>>>(a1, Wt_fc2, fc2_b, x1, out,
                                                nullptr, nullptr, nullptr, nullptr, 8192, 768, 3072);
}

// Round 6
// 282.685 us; speedup vs baseline: 1.4208x; 1.0207x over previous
//
#include <hip/hip_runtime.h>
#include <hip/hip_bf16.h>
#include <math.h>

using bf16 = __hip_bfloat16;
typedef short s16x8 __attribute__((ext_vector_type(8)));
typedef float f32x4 __attribute__((ext_vector_type(4)));
typedef float f32x16 __attribute__((ext_vector_type(16)));

#define LOG2E 1.4426950408889634f

__device__ inline unsigned short f2bf(float f) {
    bf16 h = __float2bfloat16(f);
    return __builtin_bit_cast(unsigned short, h);
}

__device__ inline float max3f(float a, float b, float c) {
    return fmaxf(fmaxf(a, b), c);   // fuses to v_max3_f32
}

// async global->LDS, 16B per lane. Dest must be wave-linear (base + lane*16).
__device__ inline void gload_lds16(const void* g, void* l) {
    __builtin_amdgcn_global_load_lds(
        (const __attribute__((address_space(1))) void*)g,
        (__attribute__((address_space(3))) void*)l, 16, 0, 0);
}

// value of the partner half (lane^32) without LDS: one permlane32_swap
__device__ inline float swap_halves(float x, int hi) {
    unsigned a = __builtin_bit_cast(unsigned, x);
    unsigned b = a;
    asm volatile("v_permlane32_swap_b32 %0, %1" : "+v"(a), "+v"(b));
    return hi ? __builtin_bit_cast(float, a) : __builtin_bit_cast(float, b);
}

__device__ inline unsigned cvtpk(float lo, float hi) {
    unsigned r;
    asm("v_cvt_pk_bf16_f32 %0, %1, %2" : "=v"(r) : "v"(lo), "v"(hi));
    return r;
}

// Build PV B-operand fragment from 8 in-lane P values (verified mapping).
__device__ inline s16x8 build_pfrag(float p0, float p1, float p2, float p3,
                                    float p4, float p5, float p6, float p7) {
    unsigned w01 = cvtpk(p0, p1);
    unsigned w23 = cvtpk(p2, p3);
    unsigned w45 = cvtpk(p4, p5);
    unsigned w67 = cvtpk(p6, p7);
    asm volatile("v_permlane32_swap_b32 %0, %1" : "+v"(w01), "+v"(w45));
    asm volatile("v_permlane32_swap_b32 %0, %1" : "+v"(w23), "+v"(w67));
    int4 t = {(int)w01, (int)w23, (int)w45, (int)w67};
    return __builtin_bit_cast(s16x8, t);
}

// ---------------------------------------------------------------------------
// Weight prep: in [K][N] fp32 row-major  ->  out [N][K] bf16 row-major (W^T)
// ---------------------------------------------------------------------------
__global__ __launch_bounds__(256) void transpose_bf16(
    const float* __restrict__ in, bf16* __restrict__ out, int K, int N)
{
    __shared__ float tile[32][33];
    const int bx = blockIdx.x * 32;  // n
    const int by = blockIdx.y * 32;  // k
    const int tx = threadIdx.x, ty = threadIdx.y;  // 32 x 8
    #pragma unroll
    for (int i = 0; i < 32; i += 8)
        tile[ty + i][tx] = in[(size_t)(by + ty + i) * N + bx + tx];
    __syncthreads();
    #pragma unroll
    for (int i = 0; i < 32; i += 8)
        out[(size_t)(bx + ty + i) * K + by + tx] = __float2bfloat16(tile[tx][ty + i]);
}

// ---------------------------------------------------------------------------
// LayerNorm over C=768, fp32 in -> bf16 out. One 256-thread block per row.
// ---------------------------------------------------------------------------
__global__ __launch_bounds__(256) void ln_kernel(
    const float* __restrict__ x, const float* __restrict__ g,
    const float* __restrict__ bb, bf16* __restrict__ out)
{
    const int row = blockIdx.x;
    const float* xr = x + (size_t)row * 768;
    float v[3];
    float s = 0.f, s2 = 0.f;
    #pragma unroll
    for (int i = 0; i < 3; ++i) {
        v[i] = xr[threadIdx.x + i * 256];
        s += v[i];
        s2 += v[i] * v[i];
    }
    #pragma unroll
    for (int off = 1; off < 64; off <<= 1) {
        s += __shfl_xor(s, off);
        s2 += __shfl_xor(s2, off);
    }
    __shared__ float rs[4], rs2[4];
    const int wave = threadIdx.x >> 6;
    if ((threadIdx.x & 63) == 0) { rs[wave] = s; rs2[wave] = s2; }
    __syncthreads();
    s = rs[0] + rs[1] + rs[2] + rs[3];
    s2 = rs2[0] + rs2[1] + rs2[2] + rs2[3];
    const float mu = s * (1.f / 768.f);
    const float var = s2 * (1.f / 768.f) - mu * mu;
    const float r = rsqrtf(var + 1e-6f);
    bf16* orow = out + (size_t)row * 768;
    #pragma unroll
    for (int i = 0; i < 3; ++i) {
        const int col = threadIdx.x + i * 256;
        orow[col] = __float2bfloat16((v[i] - mu) * r * g[col] + bb[col]);
    }
}

// ---------------------------------------------------------------------------
// GEMM: out[M][N] = A[M][K] @ Bt[N][K]^T + bias (+ residual / gelu)
// EPI: 0 = bias -> bf16 ; 1 = bias+resid -> fp32 ; 2 = bias+gelu -> bf16 ;
//      3 = fused QKV epilogue: scatter to Qb (x0.125, mask-zeroed), Kb, Vt
//          (V region goes through a per-wave LDS bounce for coalesced stores).
// ---------------------------------------------------------------------------
#define BM 128
#define BN 128
#define BK 64

template <int EPI>
__global__ __launch_bounds__(256) void gemm_bt(
    const bf16* __restrict__ A, const bf16* __restrict__ Bt,
    const float* __restrict__ bias, const float* __restrict__ resid,
    void* __restrict__ outp, const int* __restrict__ mask,
    bf16* __restrict__ Qb, bf16* __restrict__ Kb, bf16* __restrict__ Vt,
    int M, int N, int K)
{
    __shared__ alignas(16) char smem[32768];
    char* As = smem;
    char* Bs = smem + 16384;
    const int tid = threadIdx.x;
    const int lane = tid & 63;
    const int wave = tid >> 6;
    const int wm = wave >> 1, wn = wave & 1;
    const int lr = lane & 15, lg = lane >> 4;
    const int bm = blockIdx.x, bn = blockIdx.y;

    f32x4 acc[4][4] = {};

    const size_t a_row0 = (size_t)bm * BM;
    const size_t b_row0 = (size_t)bn * BN;

    for (int kt = 0; kt < K; kt += BK) {
        #pragma unroll
        for (int i = 0; i < 4; ++i) {
            const int id = tid + i * 256;
            const int row = id >> 3, c = id & 7;
            const int cs = (c ^ (row & 7)) * 8;  // inverse swizzle on source
            gload_lds16(A + (a_row0 + row) * K + kt + cs, As + id * 16);
            gload_lds16(Bt + (b_row0 + row) * K + kt + cs, Bs + id * 16);
        }
        __syncthreads();
        #pragma unroll
        for (int ks = 0; ks < 2; ++ks) {
            s16x8 af[4], bfr[4];
            #pragma unroll
            for (int mf = 0; mf < 4; ++mf) {
                const int row = wm * 64 + mf * 16 + lr;
                const int c = ks * 4 + lg;
                af[mf] = *reinterpret_cast<const s16x8*>(As + row * 128 + ((c ^ (row & 7)) * 16));
            }
            #pragma unroll
            for (int nf = 0; nf < 4; ++nf) {
                const int row = wn * 64 + nf * 16 + lr;
                const int c = ks * 4 + lg;
                bfr[nf] = *reinterpret_cast<const s16x8*>(Bs + row * 128 + ((c ^ (row & 7)) * 16));
            }
            #pragma unroll
            for (int mf = 0; mf < 4; ++mf)
                #pragma unroll
                for (int nf = 0; nf < 4; ++nf)
                    acc[mf][nf] = __builtin_amdgcn_mfma_f32_16x16x32_bf16(
                        af[mf], bfr[nf], acc[mf][nf], 0, 0, 0);
        }
        __syncthreads();
    }

    if (EPI == 3) {
        const int rq = bn / 6;                       // 0=q, 1=k, 2=v
        const int bb_ = bm >> 4;                     // batch index
        if (rq == 2) {
            // V: acc -> per-wave LDS tile [c_local 64][n_local 64] (swizzled),
            // then coalesced 16B stores to Vt[(bh*64+d)*2048 + n].
            char* Ws = smem + wave * 8192;
            #pragma unroll
            for (int nf = 0; nf < 4; ++nf) {
                const int cl = nf * 16 + lr;
                const int gn = bn * 128 + wn * 64 + nf * 16 + lr;
                const float bs = bias[gn];
                #pragma unroll
                for (int mf = 0; mf < 4; ++mf) {
                    unsigned short pk[4];
                    #pragma unroll
                    for (int i = 0; i < 4; ++i) pk[i] = f2bf(acc[mf][nf][i] + bs);
                    const int slot = (2 * mf + (lg >> 1)) ^ (cl & 7);
                    *reinterpret_cast<long long*>(Ws + cl * 128 + slot * 16 + (lg & 1) * 8) =
                        *reinterpret_cast<const long long*>(pk);
                }
            }
            __syncthreads();
            const int nb = (bm * 128 + wm * 64) & 2047;
            const int cb = (bn - 12) * 128 + wn * 64;
            #pragma unroll
            for (int r = 0; r < 8; ++r) {
                const int cl = r * 8 + (lane >> 3);
                const int j = lane & 7;
                const int4 vv = *reinterpret_cast<const int4*>(
                    Ws + cl * 128 + ((j ^ (cl & 7)) * 16));
                const int c = cb + cl;
                const int hh = c >> 6, dd = c & 63;
                *reinterpret_cast<int4*>(
                    Vt + ((size_t)(bb_ * 12 + hh) * 64 + dd) * 2048 + nb + j * 8) = vv;
            }
        } else {
            const int cb = bn * 128 - rq * 768 + wn * 64;
            bf16* dst = (rq == 0) ? Qb : Kb;
            #pragma unroll
            for (int mf = 0; mf < 4; ++mf) {
                #pragma unroll
                for (int i = 0; i < 4; ++i) {
                    const int gm = bm * 128 + wm * 64 + mf * 16 + 4 * lg + i;
                    const int n = gm & 2047;
                    const float msc = (rq == 0) ? (mask[gm] ? 0.125f : 0.f) : 1.f;
                    #pragma unroll
                    for (int nf = 0; nf < 4; ++nf) {
                        const int c = cb + nf * 16 + lr;
                        const int h = c >> 6, d = c & 63;
                        const int gn = bn * 128 + wn * 64 + nf * 16 + lr;
                        const float v = (acc[mf][nf][i] + bias[gn]) * msc;
                        dst[((size_t)(bb_ * 12 + h) * 2048 + n) * 64 + d] =
                            __float2bfloat16(v);
                    }
                }
            }
        }
        return;
    }

    #pragma unroll
    for (int mf = 0; mf < 4; ++mf) {
        #pragma unroll
        for (int i = 0; i < 4; ++i) {
            const int gm = bm * BM + wm * 64 + mf * 16 + 4 * lg + i;
            #pragma unroll
            for (int nf = 0; nf < 4; ++nf) {
                const int gn = bn * BN + wn * 64 + nf * 16 + lr;
                float v = acc[mf][nf][i] + bias[gn];
                if (EPI == 1) v += resid[(size_t)gm * N + gn];
                if (EPI == 2) {
                    // gelu(x) = x - x/(1+e^{2y}), y = 0.79788456(x+0.044715x^3)
                    const float x3 = v * v * v;
                    const float z = fmaf(x3, 0.044715f, v) * 2.3022080f;  // 2*log2e*0.79788456
                    const float e = __builtin_amdgcn_exp2f(z);
                    v = v - v * __builtin_amdgcn_rcpf(1.f + e);
                }
                if (EPI == 1)
                    reinterpret_cast<float*>(outp)[(size_t)gm * N + gn] = v;
                else
                    reinterpret_cast<bf16*>(outp)[(size_t)gm * N + gn] = __float2bfloat16(v);
            }
        }
    }
}

// ---------------------------------------------------------------------------
// Flash attention, swapped-QK^T in-register-softmax, round 6:
// 4-bit 2-row-interleaved LDS swizzle (2-way max -> conflict-free per m136),
// joint 64-key softmax with v_max3 tree, defer-max, dbuf staging, XCD remap.
// LDS tile layout: 32 rows x 256B; tile-row r, 16B-chunk s lives at
//   byte = (r>>1)*256 + (((((r&1)<<3)|s) ^ ((r>>1)&15)) << 4)
// ---------------------------------------------------------------------------
__global__ __launch_bounds__(256, 3) void attn_kernel(
    const bf16* __restrict__ Qb, const bf16* __restrict__ Kb,
    const bf16* __restrict__ Vt, bf16* __restrict__ out)
{
    __shared__ alignas(16) char Ks[2][64 * 128];
    __shared__ alignas(16) char Vs[2][64 * 128];

    // bijective XCD remap: all 16 q-blocks of a (b,h) pair on one XCD.
    const int lin = blockIdx.x;            // 768 blocks
    const int xcd = lin & 7, slot = lin >> 3;
    const int pair = xcd * 6 + (slot >> 4);   // 0..47
    const int qb = slot & 15;
    const int b = pair / 12, h = pair % 12;

    const int tid = threadIdx.x, lane = tid & 63, wave = tid >> 6;
    const int lq = lane & 31;
    const int hi = lane >> 5;
    const size_t bh = (size_t)(b * 12 + h);
    const bf16* Kh = Kb + bh * 2048 * 64;
    const bf16* Vh = Vt + bh * 64 * 2048;
    const int q0w = qb * 128 + wave * 32;

    // Q fragments: qf[ks] covers d = 16*ks + 8*hi + j   (B-operand layout)
    s16x8 qf[4];
    {
        const bf16* qp = Qb + (bh * 2048 + q0w + lq) * 64 + 8 * hi;
        #pragma unroll
        for (int ks = 0; ks < 4; ++ks)
            qf[ks] = *reinterpret_cast<const s16x8*>(qp + 16 * ks);
    }

    // staging source offsets (loop-invariant; inverse of the LDS swizzle)
    int sKoff0, sKoff1, dst0, dst1;
    size_t sVoff0, sVoff1;
    {
        const int id0 = tid;
        const int R0 = id0 >> 4;
        const int u0 = (id0 & 15) ^ (R0 & 15);
        const int rt0 = 2 * R0 + (u0 >> 3), s80 = (u0 & 7) * 8;
        sKoff0 = rt0 * 64 + s80;
        sVoff0 = (size_t)rt0 * 2048 + s80;
        dst0 = id0 * 16;
        const int id1 = tid + 256;
        const int R1 = id1 >> 4;
        const int u1 = (id1 & 15) ^ (R1 & 15);
        const int rt1 = 2 * R1 + (u1 >> 3), s81 = (u1 & 7) * 8;
        sKoff1 = rt1 * 64 + s81;
        sVoff1 = (size_t)rt1 * 2048 + s81;
        dst1 = id1 * 16;
    }

    // read-offset precompute: off(row=lq,    s) = rbase + ((s^m7)<<4)
    //                         off(row=32+lq, s) = rbase + 4096 + ((s^m7)<<4)
    const int rh = lq >> 1;
    const int m7 = rh & 7;
    const int rbase = rh * 256 + (((((lq & 1) << 3) ^ (rh & 8))) << 4);

    float m_r = -1e30f, l_r = 0.f;   // m_r in log2 domain
    f32x16 o0 = {}, o1 = {};         // O^T accumulators: d 0..31 / 32..63

    #define STAGE(buf, kb)                                                    \
        do {                                                                  \
            gload_lds16(Kh + (kb) * 4096 + sKoff0, Ks[buf] + dst0);           \
            gload_lds16(Vh + (kb) * 64 + sVoff0, Vs[buf] + dst0);             \
            gload_lds16(Kh + (kb) * 4096 + sKoff1, Ks[buf] + dst1);           \
            gload_lds16(Vh + (kb) * 64 + sVoff1, Vs[buf] + dst1);             \
        } while (0)

    STAGE(0, 0);
    __syncthreads();
    int cur = 0;

    for (int kb = 0; kb < 32; ++kb) {
        if (kb < 31) STAGE(cur ^ 1, kb + 1);
        const char* Kc = Ks[cur] + rbase;
        const char* Vc = Vs[cur] + rbase;

        // ---- S^T for both 32-key subtiles: 8 MFMAs ----
        f32x16 st0 = {}, st1 = {};
        __builtin_amdgcn_s_setprio(1);
        #pragma unroll
        for (int ks = 0; ks < 4; ++ks) {
            const int so = (((2 * ks + hi) ^ m7) << 4);
            const s16x8 kf0 = *reinterpret_cast<const s16x8*>(Kc + so);
            st0 = __builtin_amdgcn_mfma_f32_32x32x16_bf16(kf0, qf[ks], st0, 0, 0, 0);
            const s16x8 kf1 = *reinterpret_cast<const s16x8*>(Kc + 4096 + so);
            st1 = __builtin_amdgcn_mfma_f32_32x32x16_bf16(kf1, qf[ks], st1, 0, 0, 0);
        }
        __builtin_amdgcn_s_setprio(0);

        // ---- joint softmax over 64 keys, log2 domain, defer-max ----
        float a0 = max3f(st0[0], st0[1], st0[2]);
        float a1 = max3f(st0[3], st0[4], st0[5]);
        float a2 = max3f(st0[6], st0[7], st0[8]);
        float a3 = max3f(st0[9], st0[10], st0[11]);
        float a4 = max3f(st0[12], st0[13], st0[14]);
        float b0 = max3f(st1[0], st1[1], st1[2]);
        float b1 = max3f(st1[3], st1[4], st1[5]);
        float b2 = max3f(st1[6], st1[7], st1[8]);
        float b3 = max3f(st1[9], st1[10], st1[11]);
        float b4 = max3f(st1[12], st1[13], st1[14]);
        a0 = max3f(a0, a1, a2);
        a3 = max3f(a3, a4, st0[15]);
        b0 = max3f(b0, b1, b2);
        b3 = max3f(b3, b4, st1[15]);
        float mx = fmaxf(fmaxf(a0, a3), fmaxf(b0, b3));
        mx = fmaxf(mx, swap_halves(mx, hi));
        const float ml = mx * LOG2E;
        if (!__all(ml - m_r <= 8.0f)) {
            const float mnew = fmaxf(m_r, ml);
            const float alpha = __builtin_amdgcn_exp2f(m_r - mnew);
            m_r = mnew;
            l_r *= alpha;
            #pragma unroll
            for (int r = 0; r < 16; ++r) { o0[r] *= alpha; o1[r] *= alpha; }
        }
        float p0[16], p1[16];
        float rsa = 0.f, rsb = 0.f;
        #pragma unroll
        for (int r = 0; r < 16; ++r) {
            p0[r] = __builtin_amdgcn_exp2f(fmaf(st0[r], LOG2E, -m_r));
            p1[r] = __builtin_amdgcn_exp2f(fmaf(st1[r], LOG2E, -m_r));
            rsa += p0[r];
            rsb += p1[r];
        }
        float rs = rsa + rsb;
        rs += swap_halves(rs, hi);
        l_r += rs;

        // ---- P^T B-frags (4 x 16 keys) ----
        const s16x8 pf00 = build_pfrag(p0[0], p0[1], p0[2], p0[3], p0[4], p0[5], p0[6], p0[7]);
        const s16x8 pf01 = build_pfrag(p0[8], p0[9], p0[10], p0[11], p0[12], p0[13], p0[14], p0[15]);
        const s16x8 pf10 = build_pfrag(p1[0], p1[1], p1[2], p1[3], p1[4], p1[5], p1[6], p1[7]);
        const s16x8 pf11 = build_pfrag(p1[8], p1[9], p1[10], p1[11], p1[12], p1[13], p1[14], p1[15]);

        // ---- O^T += V^T * P^T : 2 d-halves x 4 key-frags ----
        __builtin_amdgcn_s_setprio(1);
        #pragma unroll
        for (int kf4 = 0; kf4 < 4; ++kf4) {
            const s16x8 pf = (kf4 == 0) ? pf00 : (kf4 == 1) ? pf01
                           : (kf4 == 2) ? pf10 : pf11;
            const int so = (((2 * kf4 + hi) ^ m7) << 4);
            const s16x8 vf0 = *reinterpret_cast<const s16x8*>(Vc + so);
            o0 = __builtin_amdgcn_mfma_f32_32x32x16_bf16(vf0, pf, o0, 0, 0, 0);
            const s16x8 vf1 = *reinterpret_cast<const s16x8*>(Vc + 4096 + so);
            o1 = __builtin_amdgcn_mfma_f32_32x32x16_bf16(vf1, pf, o1, 0, 0, 0);
        }
        __builtin_amdgcn_s_setprio(0);

        __syncthreads();
        cur ^= 1;
    }
    #undef STAGE

    // ---- epilogue: normalize and store (O^T[d][q] -> out[q][d]) ----
    const float rl = 1.0f / l_r;
    bf16* orow = out + (size_t)(b * 2048 + q0w + lq) * 768 + h * 64;
    #pragma unroll
    for (int g = 0; g < 4; ++g) {
        unsigned short pk0[4], pk1[4];
        #pragma unroll
        for (int i = 0; i < 4; ++i) {
            pk0[i] = f2bf(o0[4 * g + i] * rl);
            pk1[i] = f2bf(o1[4 * g + i] * rl);
        }
        const int d0 = 8 * g + 4 * hi;
        *reinterpret_cast<int2*>(orow + d0) = *reinterpret_cast<const int2*>(pk0);
        *reinterpret_cast<int2*>(orow + 32 + d0) = *reinterpret_cast<const int2*>(pk1);
    }
}

// ---------------------------------------------------------------------------
// Launch
// ---------------------------------------------------------------------------
extern "C" void kernel_launch(void* const* d_in, const int* in_sizes, int n_in,
                              void* d_out, int out_size, void* d_ws, size_t ws_size,
                              hipStream_t stream)
{
    (void)in_sizes; (void)n_in; (void)out_size; (void)ws_size;
    const float* x      = (const float*)d_in[0];
    const int*   mask   = (const int*)d_in[1];
    const float* ln1_g  = (const float*)d_in[2];
    const float* ln1_b  = (const float*)d_in[3];
    const float* qkv_w  = (const float*)d_in[4];
    const float* qkv_b  = (const float*)d_in[5];
    const float* proj_w = (const float*)d_in[6];
    const float* proj_b = (const float*)d_in[7];
    const float* ln2_g  = (const float*)d_in[8];
    const float* ln2_b  = (const float*)d_in[9];
    const float* fc1_w  = (const float*)d_in[10];
    const float* fc1_b  = (const float*)d_in[11];
    const float* fc2_w  = (const float*)d_in[12];
    const float* fc2_b  = (const float*)d_in[13];
    float* out = (float*)d_out;
    char* ws = (char*)d_ws;

    bf16*  Wt_qkv  = (bf16*)(ws + 0);          // [2304][768]
    bf16*  Wt_proj = (bf16*)(ws + 3538944);    // [768][768]
    bf16*  Wt_fc1  = (bf16*)(ws + 4718592);    // [3072][768]
    bf16*  Wt_fc2  = (bf16*)(ws + 9437184);    // [768][3072]
    bf16*  hbuf    = (bf16*)(ws + 14155776);   // [8192][768]
    bf16*  attnout = (bf16*)(ws + 64487424);   // [8192][768]
    float* x1      = (float*)(ws + 77070336);  // [8192][768]
    bf16*  h2      = (bf16*)(ws + 102236160);  // [8192][768]
    bf16*  a1      = (bf16*)(ws + 114819072);  // [8192][3072] (FC1 out)
    bf16*  Qb      = (bf16*)(ws + 114819072);  // overlay: [4][12][2048][64]
    bf16*  Kb      = (bf16*)(ws + 127401984);
    bf16*  Vt      = (bf16*)(ws + 139984896);

    const dim3 tb(32, 8);
    transpose_bf16<<<dim3(2304 / 32, 768 / 32), tb, 0, stream>>>(qkv_w, Wt_qkv, 768, 2304);
    transpose_bf16<<<dim3(768 / 32, 768 / 32), tb, 0, stream>>>(proj_w, Wt_proj, 768, 768);
    transpose_bf16<<<dim3(3072 / 32, 768 / 32), tb, 0, stream>>>(fc1_w, Wt_fc1, 768, 3072);
    transpose_bf16<<<dim3(768 / 32, 3072 / 32), tb, 0, stream>>>(fc2_w, Wt_fc2, 3072, 768);

    ln_kernel<<<8192, 256, 0, stream>>>(x, ln1_g, ln1_b, hbuf);
    gemm_bt<3><<<dim3(64, 18), 256, 0, stream>>>(hbuf, Wt_qkv, qkv_b, nullptr, nullptr,
                                                 mask, Qb, Kb, Vt, 8192, 2304, 768);
    attn_kernel<<<768, 256, 0, stream>>>(Qb, Kb, Vt, attnout);
    gemm_bt<1><<<dim3(64, 6), 256, 0, stream>>>(attnout, Wt_proj, proj_b, x, x1,
                                                nullptr, nullptr, nullptr, nullptr, 8192, 768, 768);
    ln_kernel<<<8192, 256, 0, stream>>>(x1, ln2_g, ln2_b, h2);
    gemm_bt<2><<<dim3(64, 24), 256, 0, stream>>>(h2, Wt_fc1, fc1_b, nullptr, a1,
                                                 nullptr, nullptr, nullptr, nullptr, 8192, 3072, 768);
    gemm_bt<1><<<dim3(64, 6), 256, 0, stream>>>(a1, Wt_fc2, fc2_b, x1, out,
                                                nullptr, nullptr, nullptr, nullptr, 8192, 768, 3072);
}